// Round 9
// baseline (308.333 us; speedup 1.0000x reference)
//
#include <hip/hip_runtime.h>
#include <stdint.h>
#include <math.h>

// Sizes
#define NN 512   // N_NODES
#define HID 64
#define LAT 256
#define TS 10
#define BAT 64

#define DEVFN static __device__ __forceinline__

DEVFN uint32_t rotl32(uint32_t v, int d) { return (v << d) | (v >> (32 - d)); }

// Threefry-2x32, 20 rounds (JAX threefry2x32_p). key=(k0,k1), count=(x0,x1).
DEVFN void threefry2x32(uint32_t k0, uint32_t k1, uint32_t x0, uint32_t x1,
                        uint32_t& o0, uint32_t& o1) {
  uint32_t ks0 = k0, ks1 = k1, ks2 = k0 ^ k1 ^ 0x1BD11BDAu;
  x0 += ks0; x1 += ks1;
  x0 += x1; x1 = rotl32(x1, 13); x1 ^= x0;
  x0 += x1; x1 = rotl32(x1, 15); x1 ^= x0;
  x0 += x1; x1 = rotl32(x1, 26); x1 ^= x0;
  x0 += x1; x1 = rotl32(x1, 6);  x1 ^= x0;
  x0 += ks1; x1 += ks2 + 1u;
  x0 += x1; x1 = rotl32(x1, 17); x1 ^= x0;
  x0 += x1; x1 = rotl32(x1, 29); x1 ^= x0;
  x0 += x1; x1 = rotl32(x1, 16); x1 ^= x0;
  x0 += x1; x1 = rotl32(x1, 24); x1 ^= x0;
  x0 += ks2; x1 += ks0 + 2u;
  x0 += x1; x1 = rotl32(x1, 13); x1 ^= x0;
  x0 += x1; x1 = rotl32(x1, 15); x1 ^= x0;
  x0 += x1; x1 = rotl32(x1, 26); x1 ^= x0;
  x0 += x1; x1 = rotl32(x1, 6);  x1 ^= x0;
  x0 += ks0; x1 += ks1 + 3u;
  x0 += x1; x1 = rotl32(x1, 17); x1 ^= x0;
  x0 += x1; x1 = rotl32(x1, 29); x1 ^= x0;
  x0 += x1; x1 = rotl32(x1, 16); x1 ^= x0;
  x0 += x1; x1 = rotl32(x1, 24); x1 ^= x0;
  x0 += ks1; x1 += ks2 + 4u;
  x0 += x1; x1 = rotl32(x1, 13); x1 ^= x0;
  x0 += x1; x1 = rotl32(x1, 15); x1 ^= x0;
  x0 += x1; x1 = rotl32(x1, 26); x1 ^= x0;
  x0 += x1; x1 = rotl32(x1, 6);  x1 ^= x0;
  x0 += ks2; x1 += ks0 + 5u;
  o0 = x0; o1 = x1;
}

DEVFN float sigmoidf_(float x) { return 1.0f / (1.0f + expf(-x)); }

// JAX gumbel from 32 random bits: uniform in [tiny, 1), g = -log(-log(u))
DEVFN float gumbel_bits(uint32_t bits) {
  const float tiny = 1.17549435e-38f;
  float f = __uint_as_float((bits >> 9) | 0x3F800000u) - 1.0f;
  float u = f * (1.0f - tiny) + tiny;
  u = fmaxf(tiny, u);
  return -logf(-logf(u));
}

// 256-thread block reduction (4 waves of 64)
DEVFN float block_red256(float v, float* red, bool ismax) {
  #pragma unroll
  for (int o = 32; o > 0; o >>= 1) {
    float w = __shfl_down(v, o, 64);
    v = ismax ? fmaxf(v, w) : v + w;
  }
  if ((threadIdx.x & 63) == 0) red[threadIdx.x >> 6] = v;
  __syncthreads();
  float r = ismax ? fmaxf(fmaxf(red[0], red[1]), fmaxf(red[2], red[3]))
                  : ((red[0] + red[1]) + (red[2] + red[3]));
  __syncthreads();
  return r;
}

// float4 dot-step, k-ascending order preserved
#define ACC4(acc, x4, w4) { acc += (x4).x * (w4).x; acc += (x4).y * (w4).y; \
                            acc += (x4).z * (w4).z; acc += (x4).w * (w4).w; }

// ---------------- wp1: x0 = X @ wp1 + bp1 (float4 k-chunk LDS) -----------------
__global__ __launch_bounds__(256) void wp1_kernel(
    const float* __restrict__ X, const float* __restrict__ wp1,
    const float* __restrict__ bp1, float* __restrict__ x0) {
  const int r0 = blockIdx.x * 4;
  const int tid = threadIdx.x, g = tid >> 6, c = tid & 63;
  __shared__ float Xb[4][NN];      // 8KB
  __shared__ float Wb[128 * 64];   // 32KB, k-chunk float4 layout
  for (int i = tid; i < 4 * NN; i += 256)
    Xb[i >> 9][i & 511] = X[r0 * NN + i];
  float acc = bp1[c];
  for (int ch = 0; ch < 4; ch++) {
    const int n0 = ch * 128;
    __syncthreads();
    for (int i = tid; i < 128 * 64; i += 256) {
      int k = i >> 6, cc = i & 63;
      Wb[((k >> 2) * 64 + cc) * 4 + (k & 3)] = wp1[(n0 + k) * 64 + cc];
    }
    __syncthreads();
    #pragma unroll 8
    for (int n4 = 0; n4 < 32; n4++) {
      float4 w4 = *(const float4*)&Wb[(n4 * 64 + c) * 4];
      float4 x4 = *(const float4*)&Xb[g][n0 + n4 * 4];
      ACC4(acc, x4, w4);
    }
  }
  x0[(r0 + g) * HID + c] = acc;
}

// ---------------- encoder layers: all weights LDS float4-staged per layer ------
__global__ __launch_bounds__(640) void enc4_kernel(
    const float* __restrict__ x0,
    const float* __restrict__ in_w, const float* __restrict__ in_b,
    const float* __restrict__ out_w, const float* __restrict__ out_b,
    const float* __restrict__ l1_w, const float* __restrict__ l1_b,
    const float* __restrict__ l2_w, const float* __restrict__ l2_b,
    const float* __restrict__ g1, const float* __restrict__ b1,
    const float* __restrict__ g2, const float* __restrict__ b2,
    float* __restrict__ x_enc) {
  const int b = blockIdx.x;
  const int tid = threadIdx.x;
  const int s = tid >> 6, c = tid & 63;
  __shared__ float WbA[12288];        // 48KB: in_w, k-chunk f4 (ncol=192)
  __shared__ float WbB[12288];        // 48KB: out_w|l1_w|l2_w, k-chunk f4 (ncol=64)
  __shared__ float xx[TS][HID];
  __shared__ float qkv[TS][192];
  __shared__ float scb[400];
  __shared__ float tmpv[TS][HID];
  __shared__ float buf2[TS][HID];
  __shared__ float mu_s[TS], rs_s[TS];

  xx[s][c] = x0[b * 640 + tid];

  for (int l = 0; l < 2; l++) {
    const float* inw = in_w + l * HID * 192; const float* inb = in_b + l * 192;
    const float* ow  = out_w + l * HID * HID; const float* ob = out_b + l * HID;
    const float* w1  = l1_w + l * HID * HID; const float* bb1 = l1_b + l * HID;
    const float* w2  = l2_w + l * HID * HID; const float* bb2 = l2_b + l * HID;
    const float* gg1 = g1 + l * HID; const float* be1 = b1 + l * HID;
    const float* gg2 = g2 + l * HID; const float* be2 = b2 + l * HID;

    __syncthreads();   // xx ready / prev-layer reads of Wb done
    for (int i = tid; i < 12288; i += 640) {
      int k = i / 192, cc = i % 192;
      WbA[((k >> 2) * 192 + cc) * 4 + (k & 3)] = inw[i];
    }
    for (int i = tid; i < 12288; i += 640) {
      int m = i >> 12, rem = i & 4095, k = rem >> 6, cc = rem & 63;
      float v = (m == 0) ? ow[rem] : (m == 1) ? w1[rem] : w2[rem];
      WbB[m * 4096 + ((k >> 2) * 64 + cc) * 4 + (k & 3)] = v;
    }
    __syncthreads();

    // qkv = x @ in_w + in_b (1920 outputs, 3/thread)
    for (int o = tid; o < TS * 192; o += 640) {
      int ss = o / 192, cc = o % 192;
      float acc = inb[cc];
      #pragma unroll
      for (int k4 = 0; k4 < 16; k4++) {
        float4 w4 = *(const float4*)&WbA[(k4 * 192 + cc) * 4];
        float4 x4 = *(const float4*)&xx[ss][k4 * 4];
        ACC4(acc, x4, w4);
      }
      qkv[ss][cc] = acc;
    }
    __syncthreads();
    // scores
    if (tid < 400) {
      int h = tid / 100, r = (tid / 10) % 10, t = tid % 10;
      float acc = 0.0f;
      for (int d = 0; d < 16; d++) acc += qkv[r][h * 16 + d] * qkv[t][64 + h * 16 + d];
      scb[tid] = acc * 0.25f;
    }
    __syncthreads();
    // softmax over t
    if (tid < 40) {
      int base = (tid / 10) * 100 + (tid % 10) * 10;
      float m = -1e30f;
      for (int t = 0; t < 10; t++) m = fmaxf(m, scb[base + t]);
      float e[10], sum = 0.0f;
      for (int t = 0; t < 10; t++) { e[t] = expf(scb[base + t] - m); sum += e[t]; }
      float inv = 1.0f / sum;
      for (int t = 0; t < 10; t++) scb[base + t] = e[t] * inv;
    }
    __syncthreads();
    // o = att @ v
    {
      const int h = c >> 4;
      float acc = 0.0f;
      for (int t = 0; t < 10; t++) acc += scb[h * 100 + s * 10 + t] * qkv[t][128 + c];
      tmpv[s][c] = acc;
    }
    __syncthreads();
    // proj + residual (WbB m=0)
    {
      float acc = ob[c] + xx[s][c];
      #pragma unroll
      for (int k4 = 0; k4 < 16; k4++) {
        float4 w4 = *(const float4*)&WbB[(k4 * 64 + c) * 4];
        float4 x4 = *(const float4*)&tmpv[s][k4 * 4];
        ACC4(acc, x4, w4);
      }
      buf2[s][c] = acc;
    }
    __syncthreads();
    // LN1 stats (bitwise order)
    if (tid < 10) {
      float m = 0.0f;
      for (int cc = 0; cc < HID; cc++) m += buf2[tid][cc];
      m *= (1.0f / 64.0f);
      float v = 0.0f;
      for (int cc = 0; cc < HID; cc++) { float d = buf2[tid][cc] - m; v += d * d; }
      v *= (1.0f / 64.0f);
      mu_s[tid] = m; rs_s[tid] = rsqrtf(v + 1e-5f);
    }
    __syncthreads();
    xx[s][c] = (buf2[s][c] - mu_s[s]) * rs_s[s] * gg1[c] + be1[c];
    __syncthreads();
    // FF1 (WbB m=1)
    {
      float acc = bb1[c];
      #pragma unroll
      for (int k4 = 0; k4 < 16; k4++) {
        float4 w4 = *(const float4*)&WbB[4096 + (k4 * 64 + c) * 4];
        float4 x4 = *(const float4*)&xx[s][k4 * 4];
        ACC4(acc, x4, w4);
      }
      tmpv[s][c] = fmaxf(acc, 0.0f);
    }
    __syncthreads();
    // FF2 + residual (WbB m=2)
    {
      float acc = bb2[c] + xx[s][c];
      #pragma unroll
      for (int k4 = 0; k4 < 16; k4++) {
        float4 w4 = *(const float4*)&WbB[8192 + (k4 * 64 + c) * 4];
        float4 x4 = *(const float4*)&tmpv[s][k4 * 4];
        ACC4(acc, x4, w4);
      }
      buf2[s][c] = acc;
    }
    __syncthreads();
    // LN2 stats
    if (tid < 10) {
      float m = 0.0f;
      for (int cc = 0; cc < HID; cc++) m += buf2[tid][cc];
      m *= (1.0f / 64.0f);
      float v = 0.0f;
      for (int cc = 0; cc < HID; cc++) { float d = buf2[tid][cc] - m; v += d * d; }
      v *= (1.0f / 64.0f);
      mu_s[tid] = m; rs_s[tid] = rsqrtf(v + 1e-5f);
    }
    __syncthreads();
    xx[s][c] = (buf2[s][c] - mu_s[s]) * rs_s[s] * gg2[c] + be2[c];
  }
  __syncthreads();
  x_enc[b * 640 + tid] = xx[s][c];
}

// ---------------- wp2: x_inst / x_lag from x_enc (W chunks in LDS) -------------
__global__ __launch_bounds__(256) void wp2_kernel(
    const float* __restrict__ x_enc, const float* __restrict__ wp2,
    const float* __restrict__ bp2,
    float* __restrict__ x_inst, float* __restrict__ x_lag) {
  const int b = blockIdx.x >> 1, half = blockIdx.x & 1;
  const int tid = threadIdx.x;
  const int n = half * 256 + tid;
  __shared__ float xxl[640];
  __shared__ float Wb[32 * 256];   // 32KB
  for (int i = tid; i < 640; i += 256) xxl[i] = x_enc[b * 640 + i];
  float accs[10];
  #pragma unroll
  for (int si = 0; si < 10; si++) accs[si] = 0.0f;
  for (int ch = 0; ch < 2; ch++) {
    __syncthreads();
    for (int i = tid; i < 32 * 256; i += 256)
      Wb[i] = wp2[(ch * 32 + (i >> 8)) * NN + half * 256 + (i & 255)];
    __syncthreads();
    for (int k = 0; k < 32; k++) {
      float w = Wb[k * 256 + tid];
      #pragma unroll
      for (int si = 0; si < 10; si++) accs[si] += xxl[si * 64 + ch * 32 + k] * w;
    }
  }
  float bias = bp2[n];
  x_inst[b * NN + n] = accs[0] + bias;
  float lag = 0.0f;
  for (int si = 1; si < 10; si++) lag += accs[si];
  x_lag[b * NN + n] = lag * (1.0f / 9.0f) + bias;
}

// ---------------- adjacency: gram + gumbel + softmax + sigmoid -----------------
__global__ __launch_bounds__(256) void adj_kernel(
    const float* __restrict__ x_inst, const float* __restrict__ x_lag,
    const float* __restrict__ es_now, const float* __restrict__ es_lag,
    const float* __restrict__ prior, float* __restrict__ out) {
  const int k = blockIdx.x & 511;
  const int v = blockIdx.x >> 9;       // 0 = now, 1 = lag
  const int tid = threadIdx.x;
  const float* xs = v ? x_lag : x_inst;
  const float* es = v ? es_lag : es_now;
  __shared__ float ck[BAT];
  __shared__ float red[4];
  if (tid < BAT) ck[tid] = xs[tid * NN + k];
  __syncthreads();
  uint32_t ka, kb, t0, t1;
  threefry2x32(0u, 42u, 0u, (uint32_t)v, ka, kb);
  float vals[2];
  #pragma unroll
  for (int jj = 0; jj < 2; jj++) {
    int j = tid + jj * 256;
    float acc = 0.0f;
    for (int bb = 0; bb < BAT; bb++) acc += ck[bb] * xs[bb * NN + j];
    if (v) acc = sigmoidf_(acc);
    threefry2x32(ka, kb, 0u, (uint32_t)(k * NN + j), t0, t1);
    vals[jj] = acc + gumbel_bits(t0 ^ t1);
  }
  float m = block_red256(fmaxf(vals[0], vals[1]), red, true);
  float e0 = expf(vals[0] - m), e1 = expf(vals[1] - m);
  float s = block_red256(e0 + e1, red, false);
  float inv = 1.0f / s;
  #pragma unroll
  for (int jj = 0; jj < 2; jj++) {
    int j = tid + jj * 256;
    float a = (jj ? e1 : e0) * inv;
    float t = es[k * NN + j] + prior[k * NN + j] + a;
    float sg = sigmoidf_(t);
    sg = fminf(fmaxf(sg, 0.0f), 1.0f);
    if (j == k) sg = 0.0f;
    if (sg == 0.0f) sg = 1e-8f;
    out[v * NN * NN + k * NN + j] = sg;
  }
}

// ---------------- RealNVP flow ------------------------------------------------
__global__ __launch_bounds__(128) void flow_kernel(
    const float* __restrict__ Z, const float* __restrict__ fs_w, const float* __restrict__ fs_b,
    const float* __restrict__ ft_w, const float* __restrict__ ft_b, float* __restrict__ z2p) {
  const int n = blockIdx.x, c = threadIdx.x;
  __shared__ float z1[128];
  z1[c] = Z[n * LAT + c];
  __syncthreads();
  float a = fs_b[c], t = ft_b[c];
  for (int k = 0; k < 128; k++) {
    float zz = z1[k];
    a += zz * fs_w[k * 128 + c];
    t += zz * ft_w[k * 128 + c];
  }
  z2p[n * 128 + c] = sigmoidf_(a) * Z[n * LAT + 128 + c] + t;
}

// ---------------- gi table: only 100 distinct time values exist ----------------
__global__ __launch_bounds__(384) void gitab_kernel(
    const float* __restrict__ w_ih, const float* __restrict__ b_ih,
    float* __restrict__ gi_table) {
  const int v = blockIdx.x;      // 0..99
  const int t = threadIdx.x;     // col 0..383
  __shared__ float temb[256];
  if (t < 256) {
    float fr = (float)exp((double)(t & 127) * (10.0 / 127.0));  // np-style f64 -> f32
    float arg = (float)v * fr;
    temb[t] = (t < 128) ? sinf(arg) : cosf(arg);
  }
  __syncthreads();
  float acc = b_ih[t];
  for (int k = 0; k < 256; k++) acc += temb[k] * w_ih[k * 384 + t];
  gi_table[v * 384 + t] = acc;
}

// ---------------- w_hh transpose: w_hhT[t][k] = w_hh[k*384+t] ------------------
__global__ __launch_bounds__(256) void whht_kernel(
    const float* __restrict__ w_hh, float* __restrict__ w_hhT) {
  const int i = blockIdx.x * 256 + threadIdx.x;   // 192 blocks, 49152 elems
  const int t = i >> 7, k = i & 127;
  w_hhT[i] = w_hh[k * 384 + t];
}

// ---------------- GRU: 2 nodes/block; (384,2) -> 256 VGPR budget, no spill -----
__global__ __launch_bounds__(384, 2) void gru_kernel4(
    const int* __restrict__ tctx, const float* __restrict__ w_hhT,
    const float* __restrict__ b_hh, const float* __restrict__ gi_table,
    const float* __restrict__ tp_w, const float* __restrict__ tp_b,
    const float* __restrict__ z2p, float* __restrict__ z2f) {
  const int n0 = blockIdx.x * 2, t = threadIdx.x;
  __shared__ float h[2][128];
  __shared__ float sums[2][256];   // gi+gh for r,z cols
  __shared__ float ghn[2][128];    // gh for n cols
  __shared__ float gin[2][128];    // gi for n cols
  float4 whh[32];
  const float4* wt4 = (const float4*)(w_hhT + t * 128);
  #pragma unroll
  for (int k4 = 0; k4 < 32; k4++) whh[k4] = wt4[k4];
  float gisA[10], gisB[10];
  #pragma unroll
  for (int s = 0; s < 10; s++) {
    gisA[s] = gi_table[tctx[n0 * 10 + s] * 384 + t];
    gisB[s] = gi_table[tctx[(n0 + 1) * 10 + s] * 384 + t];
  }
  float tpw[10];
  #pragma unroll
  for (int s = 0; s < 10; s++) tpw[s] = tp_w[s];
  const float bhh = b_hh[t];
  if (t < 256) h[t >> 7][t & 127] = 0.0f;
  float acc_tp = 0.0f;
  __syncthreads();
  #pragma unroll
  for (int s = 0; s < 10; s++) {
    float accA = bhh, accB = bhh;
    const float4* hA = (const float4*)h[0];
    const float4* hB = (const float4*)h[1];
    #pragma unroll
    for (int k4 = 0; k4 < 32; k4++) {
      float4 w4 = whh[k4];
      float4 a4 = hA[k4];
      float4 b4 = hB[k4];
      ACC4(accA, a4, w4);
      ACC4(accB, b4, w4);
    }
    if (t < 256) { sums[0][t] = gisA[s] + accA; sums[1][t] = gisB[s] + accB; }
    else {
      ghn[0][t - 256] = accA; gin[0][t - 256] = gisA[s];
      ghn[1][t - 256] = accB; gin[1][t - 256] = gisB[s];
    }
    __syncthreads();
    if (t < 256) {
      const int g = t >> 7, c = t & 127;
      float r = sigmoidf_(sums[g][c]);
      float z = sigmoidf_(sums[g][128 + c]);
      float nn2 = tanhf(gin[g][c] + r * ghn[g][c]);
      float hn = (1.0f - z) * nn2 + z * h[g][c];
      h[g][c] = hn;
      acc_tp += hn * tpw[s];
    }
    __syncthreads();
  }
  if (t < 256) {
    const int g = t >> 7, c = t & 127;
    z2f[(n0 + g) * 128 + c] = z2p[(n0 + g) * 128 + c] + acc_tp + tp_b[0];
  }
}

// ---------------- znA: zn_ws = concat(z1,z2f) @ ltn_w + b (4 nodes/block) ------
__global__ __launch_bounds__(256) void znA_kernel(
    const float* __restrict__ Z, const float* __restrict__ z2f,
    const float* __restrict__ ltn_w, const float* __restrict__ ltn_b,
    float* __restrict__ zn_ws) {
  const int nt = blockIdx.x >> 2, cg = blockIdx.x & 3;
  const int tid = threadIdx.x;
  const int oo = tid & 127, gsel = tid >> 7;
  const int o = cg * 128 + oo;
  const int n0 = nt * 4;
  __shared__ float zcat[4][LAT];   // 4KB
  for (int i = tid; i < 4 * LAT; i += 256) {
    int g = i >> 8, k = i & 255;
    zcat[g][k] = (k < 128) ? Z[(n0 + g) * LAT + k] : z2f[(n0 + g) * 128 + (k - 128)];
  }
  __syncthreads();
  const float bias = ltn_b[o];
  float accA = bias, accB = bias;
  const int g0 = gsel, g1 = gsel + 2;
  for (int k = 0; k < LAT; k++) {
    float w = ltn_w[k * NN + o];
    accA += zcat[g0][k] * w;
    accB += zcat[g1][k] * w;
  }
  zn_ws[(n0 + g0) * NN + o] = accA;
  zn_ws[(n0 + g1) * NN + o] = accB;
}

// ---------------- znB: xl/xr = zn_ws @ gat_w{l,r} + b (4 nodes/block) ----------
__global__ __launch_bounds__(256) void znB_kernel(
    const float* __restrict__ zn_ws,
    const float* __restrict__ wl, const float* __restrict__ bl,
    const float* __restrict__ wr, const float* __restrict__ br,
    float* __restrict__ xl, float* __restrict__ xr) {
  const int nt = blockIdx.x >> 2, cg = blockIdx.x & 3;
  const int tid = threadIdx.x;
  const int o = cg * 64 + (tid & 63), g = tid >> 6;
  const int n = nt * 4 + g;
  __shared__ float znr[4][NN];   // 8KB
  for (int i = tid; i < 4 * NN; i += 256)
    znr[i >> 9][i & 511] = zn_ws[(nt * 4 + (i >> 9)) * NN + (i & 511)];
  __syncthreads();
  float accL = bl[o], accR = br[o];
  for (int k = 0; k < NN; k++) {
    float z = znr[g][k];
    accL += z * wl[k * 256 + o];
    accR += z * wr[k * 256 + o];
  }
  xl[n * 256 + o] = accL;
  xr[n * 256 + o] = accR;
}

// ---------------- gatE: e[i][h][j] for 32i x 32j tile per block ----------------
// grid 256 = 16 it x 16 jt. thread: h=tid&3, jg=(tid>>2)&7, ig=tid>>5.
// LDS tiles in k-chunk float4 layout [c4][row][4] -> aligned b128 reads.
__global__ __launch_bounds__(256) void gatE_kernel(
    const float* __restrict__ xl, const float* __restrict__ xr,
    const float* __restrict__ attw, float* __restrict__ e_ws) {
  const int it = blockIdx.x >> 4, jt = blockIdx.x & 15;
  const int tid = threadIdx.x;
  const int h = tid & 3, jg = (tid >> 2) & 7, ig = tid >> 5;
  __shared__ float xlt[8192];   // 32KB [c4 64][j 32][4]
  __shared__ float xrt[8192];   // 32KB
  __shared__ float awl[256];
  for (int i = tid; i < 8192; i += 256) {
    int j = i >> 8, c = i & 255;
    xlt[((c >> 2) * 32 + j) * 4 + (c & 3)] = xl[(jt * 32 + j) * 256 + c];
    xrt[((c >> 2) * 32 + j) * 4 + (c & 3)] = xr[(it * 32 + j) * 256 + c];
  }
  awl[tid] = attw[tid];
  __syncthreads();
  float acc[4][4];
  #pragma unroll
  for (int a = 0; a < 4; a++)
    #pragma unroll
    for (int b2 = 0; b2 < 4; b2++) acc[a][b2] = 0.0f;
  #pragma unroll
  for (int c4 = 0; c4 < 16; c4++) {
    const int cb = (h * 16 + c4) * 32;
    float4 aw4 = *(const float4*)&awl[h * 64 + c4 * 4];
    float4 xl4[4], xr4[4];
    #pragma unroll
    for (int q = 0; q < 4; q++) {
      xl4[q] = *(const float4*)&xlt[(cb + jg * 4 + q) * 4];
      xr4[q] = *(const float4*)&xrt[(cb + ig * 4 + q) * 4];
    }
    #pragma unroll
    for (int iq = 0; iq < 4; iq++) {
      #pragma unroll
      for (int jq = 0; jq < 4; jq++) {
        float a0 = xr4[iq].x + xl4[jq].x; a0 = (a0 >= 0.0f) ? a0 : 0.2f * a0;
        float a1 = xr4[iq].y + xl4[jq].y; a1 = (a1 >= 0.0f) ? a1 : 0.2f * a1;
        float a2 = xr4[iq].z + xl4[jq].z; a2 = (a2 >= 0.0f) ? a2 : 0.2f * a2;
        float a3 = xr4[iq].w + xl4[jq].w; a3 = (a3 >= 0.0f) ? a3 : 0.2f * a3;
        float s = acc[iq][jq];
        s += a0 * aw4.x; s += a1 * aw4.y; s += a2 * aw4.z; s += a3 * aw4.w;
        acc[iq][jq] = s;
      }
    }
  }
  #pragma unroll
  for (int iq = 0; iq < 4; iq++) {
    float4 v = make_float4(acc[iq][0], acc[iq][1], acc[iq][2], acc[iq][3]);
    *(float4*)&e_ws[(it * 32 + ig * 4 + iq) * 2048 + h * 512 + jt * 32 + jg * 4] = v;
  }
}

// ---------------- gatS: softmax over j per (i, h), in-place on e_ws ------------
__global__ __launch_bounds__(256) void gatS_kernel(float* __restrict__ e_ws) {
  const int i = blockIdx.x, tid = threadIdx.x;
  __shared__ float red[4];
  float* er = e_ws + i * 2048;
  for (int h = 0; h < 4; h++) {
    float v0 = er[h * 512 + tid], v1 = er[h * 512 + 256 + tid];
    float m = block_red256(fmaxf(v0, v1), red, true);
    float e0 = expf(v0 - m), e1 = expf(v1 - m);
    float s = block_red256(e0 + e1, red, false);
    float inv = 1.0f / s;
    er[h * 512 + tid] = e0 * inv;
    er[h * 512 + 256 + tid] = e1 * inv;
  }
}

// ---------------- gatX: x_emb = alpha @ xl + gbias -----------------------------
// grid 256 = 64 it (8 i each) x 4 h. thread: cq=tid&15, jp=(tid>>4)&3, ip=tid>>6.
// j split across jp lanes; shfl_xor(16,32) reduces the 4 partials.
__global__ __launch_bounds__(256) void gatX_kernel(
    const float* __restrict__ e_ws, const float* __restrict__ xl,
    const float* __restrict__ gbias, float* __restrict__ xemb) {
  const int it = blockIdx.x >> 2, h = blockIdx.x & 3;
  const int tid = threadIdx.x;
  const int cq = tid & 15, jp = (tid >> 4) & 3, ip = tid >> 6;
  __shared__ float al[8][512];   // 16KB alpha rows for this head
  for (int i = tid; i < 8 * 512; i += 256)
    al[i >> 9][i & 511] = e_ws[(it * 8 + (i >> 9)) * 2048 + h * 512 + (i & 511)];
  __syncthreads();
  float acc[2][4];
  #pragma unroll
  for (int ii = 0; ii < 2; ii++)
    #pragma unroll
    for (int q = 0; q < 4; q++) acc[ii][q] = 0.0f;
  for (int js = 0; js < 128; js++) {
    const int j = js * 4 + jp;
    float4 x4 = *(const float4*)&xl[j * 256 + h * 64 + cq * 4];
    #pragma unroll
    for (int ii = 0; ii < 2; ii++) {
      float a = al[ip * 2 + ii][j];
      acc[ii][0] += a * x4.x; acc[ii][1] += a * x4.y;
      acc[ii][2] += a * x4.z; acc[ii][3] += a * x4.w;
    }
  }
  #pragma unroll
  for (int ii = 0; ii < 2; ii++)
    #pragma unroll
    for (int q = 0; q < 4; q++) {
      float v = acc[ii][q];
      v += __shfl_xor(v, 16, 64);
      v += __shfl_xor(v, 32, 64);
      acc[ii][q] = v;
    }
  if (jp == 0) {
    #pragma unroll
    for (int ii = 0; ii < 2; ii++) {
      const int i = it * 8 + ip * 2 + ii;
      const int o = h * 64 + cq * 4;
      float4 v = make_float4(acc[ii][0] + gbias[o],     acc[ii][1] + gbias[o + 1],
                             acc[ii][2] + gbias[o + 2], acc[ii][3] + gbias[o + 3]);
      *(float4*)&xemb[i * 256 + o] = v;
    }
  }
}

// ---------------- fallback fused GAT (2 targets/block) if ws too small ---------
__global__ __launch_bounds__(256) void gat_fused_kernel(
    const float* __restrict__ xl, const float* __restrict__ xr,
    const float* __restrict__ attw, const float* __restrict__ gbias,
    float* __restrict__ xemb) {
  const int i0 = blockIdx.x * 2, tid = threadIdx.x;
  __shared__ float xri[2][256];
  __shared__ float aw[256];
  __shared__ float e[2][4][NN];
  __shared__ float part[4][2][256];
  __shared__ float red[4];
  xri[0][tid] = xr[i0 * 256 + tid];
  xri[1][tid] = xr[(i0 + 1) * 256 + tid];
  aw[tid] = attw[tid];
  __syncthreads();
  #pragma unroll
  for (int jj = 0; jj < 2; jj++) {
    const int j = tid + jj * 256;
    const float4* xl4 = (const float4*)(xl + j * 256);
    #pragma unroll
    for (int hh = 0; hh < 4; hh++) {
      float accA = 0.0f, accB = 0.0f;
      #pragma unroll 4
      for (int c4 = 0; c4 < 16; c4++) {
        float4 v = xl4[hh * 16 + c4];
        const int cb = hh * 64 + c4 * 4;
        float w0 = aw[cb + 0], w1 = aw[cb + 1], w2 = aw[cb + 2], w3 = aw[cb + 3];
        float a0 = xri[0][cb + 0] + v.x; a0 = (a0 >= 0.0f) ? a0 : 0.2f * a0;
        float a1 = xri[0][cb + 1] + v.y; a1 = (a1 >= 0.0f) ? a1 : 0.2f * a1;
        float a2 = xri[0][cb + 2] + v.z; a2 = (a2 >= 0.0f) ? a2 : 0.2f * a2;
        float a3 = xri[0][cb + 3] + v.w; a3 = (a3 >= 0.0f) ? a3 : 0.2f * a3;
        accA += a0 * w0; accA += a1 * w1; accA += a2 * w2; accA += a3 * w3;
        float b0 = xri[1][cb + 0] + v.x; b0 = (b0 >= 0.0f) ? b0 : 0.2f * b0;
        float b1 = xri[1][cb + 1] + v.y; b1 = (b1 >= 0.0f) ? b1 : 0.2f * b1;
        float b2 = xri[1][cb + 2] + v.z; b2 = (b2 >= 0.0f) ? b2 : 0.2f * b2;
        float b3 = xri[1][cb + 3] + v.w; b3 = (b3 >= 0.0f) ? b3 : 0.2f * b3;
        accB += b0 * w0; accB += b1 * w1; accB += b2 * w2; accB += b3 * w3;
      }
      e[0][hh][j] = accA;
      e[1][hh][j] = accB;
    }
  }
  __syncthreads();
  for (int ii = 0; ii < 2; ii++) {
    for (int hh = 0; hh < 4; hh++) {
      float v0 = e[ii][hh][tid], v1 = e[ii][hh][tid + 256];
      float m = block_red256(fmaxf(v0, v1), red, true);
      float e0 = expf(v0 - m), e1 = expf(v1 - m);
      float ssum = block_red256(e0 + e1, red, false);
      float inv = 1.0f / ssum;
      e[ii][hh][tid] = e0 * inv;
      e[ii][hh][tid + 256] = e1 * inv;
    }
  }
  __syncthreads();
  {
    const int w = tid >> 6, lane = tid & 63;
    float a0 = 0.0f, a1 = 0.0f, a2 = 0.0f, a3 = 0.0f;
    float b0 = 0.0f, b1 = 0.0f, b2 = 0.0f, b3 = 0.0f;
    const int j0 = w * 128;
    for (int j = j0; j < j0 + 128; j++) {
      const float* xlr = xl + j * 256 + lane;
      float x0 = xlr[0], x1 = xlr[64], x2 = xlr[128], x3 = xlr[192];
      a0 += e[0][0][j] * x0; a1 += e[0][1][j] * x1;
      a2 += e[0][2][j] * x2; a3 += e[0][3][j] * x3;
      b0 += e[1][0][j] * x0; b1 += e[1][1][j] * x1;
      b2 += e[1][2][j] * x2; b3 += e[1][3][j] * x3;
    }
    part[w][0][lane]       = a0;
    part[w][0][64 + lane]  = a1;
    part[w][0][128 + lane] = a2;
    part[w][0][192 + lane] = a3;
    part[w][1][lane]       = b0;
    part[w][1][64 + lane]  = b1;
    part[w][1][128 + lane] = b2;
    part[w][1][192 + lane] = b3;
  }
  __syncthreads();
  {
    float accA = ((part[0][0][tid] + part[1][0][tid]) + part[2][0][tid]) + part[3][0][tid];
    float accB = ((part[0][1][tid] + part[1][1][tid]) + part[2][1][tid]) + part[3][1][tid];
    float gb = gbias[tid];
    xemb[i0 * 256 + tid] = accA + gb;
    xemb[(i0 + 1) * 256 + tid] = accB + gb;
  }
}

// ---------------- ml = x_emb @ gl_w + gl_b (tiled); mean/scale epilogue --------
__global__ __launch_bounds__(256) void glgemm_kernel(
    const float* __restrict__ xemb, const float* __restrict__ gl_w,
    const float* __restrict__ gl_b, float* __restrict__ out_mean,
    float* __restrict__ out_scale) {
  const int ct = blockIdx.x & 15, it = blockIdx.x >> 4;
  const int tid = threadIdx.x;
  const int i0 = it * 16, col = ct * 64 + (tid & 63), ti = tid >> 6;
  __shared__ float xe[16][LAT];   // 16KB
  for (int o = tid; o < 16 * LAT; o += 256) {
    xe[o >> 8][o & 255] = xemb[(i0 + (o >> 8)) * LAT + (o & 255)];
  }
  __syncthreads();
  const float bias = gl_b[col];
  float acc0 = bias, acc1 = bias, acc2 = bias, acc3 = bias;
  const int r0 = ti * 4;
  #pragma unroll 4
  for (int k = 0; k < LAT; k++) {
    float w = gl_w[k * 1024 + col];
    acc0 += xe[r0 + 0][k] * w;
    acc1 += xe[r0 + 1][k] * w;
    acc2 += xe[r0 + 2][k] * w;
    acc3 += xe[r0 + 3][k] * w;
  }
  float accs[4] = {acc0, acc1, acc2, acc3};
  if (col < 512) {
    #pragma unroll
    for (int q = 0; q < 4; q++) out_mean[(i0 + r0 + q) * NN + col] = accs[q];
  } else {
    #pragma unroll
    for (int q = 0; q < 4; q++) {
      float lv = fminf(fmaxf(accs[q], -5.0f), 2.0f);
      out_scale[(i0 + r0 + q) * NN + (col - 512)] = expf(0.5f * lv);
    }
  }
}

extern "C" void kernel_launch(void* const* d_in, const int* in_sizes, int n_in,
                              void* d_out, int out_size, void* d_ws, size_t ws_size,
                              hipStream_t stream) {
  (void)in_sizes; (void)n_in; (void)out_size;
  const float* X        = (const float*)d_in[0];
  const float* Z        = (const float*)d_in[1];
  const float* es_now   = (const float*)d_in[2];
  const float* es_lag   = (const float*)d_in[3];
  const float* prior    = (const float*)d_in[4];
  const float* wp1      = (const float*)d_in[5];
  const float* bp1      = (const float*)d_in[6];
  const float* enc_in_w = (const float*)d_in[7];
  const float* enc_in_b = (const float*)d_in[8];
  const float* enc_out_w= (const float*)d_in[9];
  const float* enc_out_b= (const float*)d_in[10];
  const float* enc_l1_w = (const float*)d_in[11];
  const float* enc_l1_b = (const float*)d_in[12];
  const float* enc_l2_w = (const float*)d_in[13];
  const float* enc_l2_b = (const float*)d_in[14];
  const float* enc_g1   = (const float*)d_in[15];
  const float* enc_b1   = (const float*)d_in[16];
  const float* enc_g2   = (const float*)d_in[17];
  const float* enc_b2   = (const float*)d_in[18];
  const float* wp2      = (const float*)d_in[19];
  const float* bp2      = (const float*)d_in[20];
  const float* fs_w     = (const float*)d_in[21];
  const float* fs_b     = (const float*)d_in[22];
  const float* ft_w     = (const float*)d_in[23];
  const float* ft_b     = (const float*)d_in[24];
  const float* gru_w_ih = (const float*)d_in[25];
  const float* gru_w_hh = (const float*)d_in[26];
  const float* gru_b_ih = (const float*)d_in[27];
  const float* gru_b_hh = (const float*)d_in[28];
  const float* tp_w     = (const float*)d_in[29];
  const float* tp_b     = (const float*)d_in[30];
  const float* ltn_w    = (const float*)d_in[31];
  const float* ltn_b    = (const float*)d_in[32];
  const float* gat_wl   = (const float*)d_in[33];
  const float* gat_bl   = (const float*)d_in[34];
  const float* gat_wr   = (const float*)d_in[35];
  const float* gat_br   = (const float*)d_in[36];
  const float* gat_att  = (const float*)d_in[37];
  const float* gat_bias = (const float*)d_in[38];
  const float* gl_w     = (const float*)d_in[39];
  const float* gl_b     = (const float*)d_in[40];
  const int*   tctx     = (const int*)d_in[41];

  float* out = (float*)d_out;
  float* ws  = (float*)d_ws;
  // ws layout (floats)
  float* x_inst   = ws;                // 64*512
  float* x_lag    = ws + 32768;        // 64*512
  float* z2p      = ws + 65536;        // 512*128
  float* z2f      = ws + 131072;       // 512*128
  float* xl       = ws + 196608;       // 512*256
  float* xr       = ws + 327680;       // 512*256
  float* gi_table = ws + 458752;       // 100*384
  float* xemb     = ws + 497152;       // 512*256
  float* x0       = ws + 628224;       // 640*64
  float* x_enc    = ws + 669184;       // 640*64
  float* zn_ws    = ws + 710144;       // 512*512
  float* e_ws     = ws + 972288;       // 512*2048 (4MB) — only if ws big enough
  float* w_hhT    = zn_ws;             // aliased; gru done before znA writes

  const bool big_ws = ws_size >= (size_t)(972288 + 512 * 2048) * 4;

  whht_kernel<<<dim3(192), dim3(256), 0, stream>>>(gru_w_hh, w_hhT);
  wp1_kernel<<<dim3(160), dim3(256), 0, stream>>>(X, wp1, bp1, x0);
  enc4_kernel<<<dim3(BAT), dim3(640), 0, stream>>>(
      x0, enc_in_w, enc_in_b, enc_out_w, enc_out_b,
      enc_l1_w, enc_l1_b, enc_l2_w, enc_l2_b,
      enc_g1, enc_b1, enc_g2, enc_b2, x_enc);
  wp2_kernel<<<dim3(128), dim3(256), 0, stream>>>(x_enc, wp2, bp2, x_inst, x_lag);
  adj_kernel<<<dim3(2 * NN), dim3(256), 0, stream>>>(
      x_inst, x_lag, es_now, es_lag, prior, out);
  gitab_kernel<<<dim3(100), dim3(384), 0, stream>>>(gru_w_ih, gru_b_ih, gi_table);
  flow_kernel<<<dim3(NN), dim3(128), 0, stream>>>(Z, fs_w, fs_b, ft_w, ft_b, z2p);
  gru_kernel4<<<dim3(NN / 2), dim3(384), 0, stream>>>(
      tctx, w_hhT, gru_b_hh, gi_table, tp_w, tp_b, z2p, z2f);
  znA_kernel<<<dim3(512), dim3(256), 0, stream>>>(Z, z2f, ltn_w, ltn_b, zn_ws);
  znB_kernel<<<dim3(512), dim3(256), 0, stream>>>(
      zn_ws, gat_wl, gat_bl, gat_wr, gat_br, xl, xr);
  if (big_ws) {
    gatE_kernel<<<dim3(256), dim3(256), 0, stream>>>(xl, xr, gat_att, e_ws);
    gatS_kernel<<<dim3(NN), dim3(256), 0, stream>>>(e_ws);
    gatX_kernel<<<dim3(256), dim3(256), 0, stream>>>(e_ws, xl, gat_bias, xemb);
  } else {
    gat_fused_kernel<<<dim3(NN / 2), dim3(256), 0, stream>>>(
        xl, xr, gat_att, gat_bias, xemb);
  }
  glgemm_kernel<<<dim3(512), dim3(256), 0, stream>>>(
      xemb, gl_w, gl_b, out + 2 * NN * NN, out + 3 * NN * NN);
}

// Round 10
// 293.979 us; speedup vs baseline: 1.0488x; 1.0488x over previous
//
#include <hip/hip_runtime.h>
#include <stdint.h>
#include <math.h>

// Sizes
#define NN 512   // N_NODES
#define HID 64
#define LAT 256
#define TS 10
#define BAT 64

#define DEVFN static __device__ __forceinline__

DEVFN uint32_t rotl32(uint32_t v, int d) { return (v << d) | (v >> (32 - d)); }

// Threefry-2x32, 20 rounds (JAX threefry2x32_p). key=(k0,k1), count=(x0,x1).
DEVFN void threefry2x32(uint32_t k0, uint32_t k1, uint32_t x0, uint32_t x1,
                        uint32_t& o0, uint32_t& o1) {
  uint32_t ks0 = k0, ks1 = k1, ks2 = k0 ^ k1 ^ 0x1BD11BDAu;
  x0 += ks0; x1 += ks1;
  x0 += x1; x1 = rotl32(x1, 13); x1 ^= x0;
  x0 += x1; x1 = rotl32(x1, 15); x1 ^= x0;
  x0 += x1; x1 = rotl32(x1, 26); x1 ^= x0;
  x0 += x1; x1 = rotl32(x1, 6);  x1 ^= x0;
  x0 += ks1; x1 += ks2 + 1u;
  x0 += x1; x1 = rotl32(x1, 17); x1 ^= x0;
  x0 += x1; x1 = rotl32(x1, 29); x1 ^= x0;
  x0 += x1; x1 = rotl32(x1, 16); x1 ^= x0;
  x0 += x1; x1 = rotl32(x1, 24); x1 ^= x0;
  x0 += ks2; x1 += ks0 + 2u;
  x0 += x1; x1 = rotl32(x1, 13); x1 ^= x0;
  x0 += x1; x1 = rotl32(x1, 15); x1 ^= x0;
  x0 += x1; x1 = rotl32(x1, 26); x1 ^= x0;
  x0 += x1; x1 = rotl32(x1, 6);  x1 ^= x0;
  x0 += ks0; x1 += ks1 + 3u;
  x0 += x1; x1 = rotl32(x1, 17); x1 ^= x0;
  x0 += x1; x1 = rotl32(x1, 29); x1 ^= x0;
  x0 += x1; x1 = rotl32(x1, 16); x1 ^= x0;
  x0 += x1; x1 = rotl32(x1, 24); x1 ^= x0;
  x0 += ks1; x1 += ks2 + 4u;
  x0 += x1; x1 = rotl32(x1, 13); x1 ^= x0;
  x0 += x1; x1 = rotl32(x1, 15); x1 ^= x0;
  x0 += x1; x1 = rotl32(x1, 26); x1 ^= x0;
  x0 += x1; x1 = rotl32(x1, 6);  x1 ^= x0;
  x0 += ks2; x1 += ks0 + 5u;
  o0 = x0; o1 = x1;
}

DEVFN float sigmoidf_(float x) { return 1.0f / (1.0f + expf(-x)); }

// JAX gumbel from 32 random bits: uniform in [tiny, 1), g = -log(-log(u))
DEVFN float gumbel_bits(uint32_t bits) {
  const float tiny = 1.17549435e-38f;
  float f = __uint_as_float((bits >> 9) | 0x3F800000u) - 1.0f;
  float u = f * (1.0f - tiny) + tiny;
  u = fmaxf(tiny, u);
  return -logf(-logf(u));
}

// 256-thread block reduction (4 waves of 64)
DEVFN float block_red256(float v, float* red, bool ismax) {
  #pragma unroll
  for (int o = 32; o > 0; o >>= 1) {
    float w = __shfl_down(v, o, 64);
    v = ismax ? fmaxf(v, w) : v + w;
  }
  if ((threadIdx.x & 63) == 0) red[threadIdx.x >> 6] = v;
  __syncthreads();
  float r = ismax ? fmaxf(fmaxf(red[0], red[1]), fmaxf(red[2], red[3]))
                  : ((red[0] + red[1]) + (red[2] + red[3]));
  __syncthreads();
  return r;
}

// float4 dot-step, k-ascending order preserved
#define ACC4(acc, x4, w4) { acc += (x4).x * (w4).x; acc += (x4).y * (w4).y; \
                            acc += (x4).z * (w4).z; acc += (x4).w * (w4).w; }

// ---------------- wp1: x0 = X @ wp1 + bp1 (float4 k-chunk LDS) -----------------
__global__ __launch_bounds__(256) void wp1_kernel(
    const float* __restrict__ X, const float* __restrict__ wp1,
    const float* __restrict__ bp1, float* __restrict__ x0) {
  const int r0 = blockIdx.x * 4;
  const int tid = threadIdx.x, g = tid >> 6, c = tid & 63;
  __shared__ float Xb[4][NN];      // 8KB
  __shared__ float Wb[128 * 64];   // 32KB, k-chunk float4 layout
  for (int i = tid; i < 4 * NN; i += 256)
    Xb[i >> 9][i & 511] = X[r0 * NN + i];
  float acc = bp1[c];
  for (int ch = 0; ch < 4; ch++) {
    const int n0 = ch * 128;
    __syncthreads();
    for (int i = tid; i < 128 * 64; i += 256) {
      int k = i >> 6, cc = i & 63;
      Wb[((k >> 2) * 64 + cc) * 4 + (k & 3)] = wp1[(n0 + k) * 64 + cc];
    }
    __syncthreads();
    #pragma unroll 8
    for (int n4 = 0; n4 < 32; n4++) {
      float4 w4 = *(const float4*)&Wb[(n4 * 64 + c) * 4];
      float4 x4 = *(const float4*)&Xb[g][n0 + n4 * 4];
      ACC4(acc, x4, w4);
    }
  }
  x0[(r0 + g) * HID + c] = acc;
}

// ---------------- encoder layers: all weights LDS float4-staged per layer ------
__global__ __launch_bounds__(640) void enc4_kernel(
    const float* __restrict__ x0,
    const float* __restrict__ in_w, const float* __restrict__ in_b,
    const float* __restrict__ out_w, const float* __restrict__ out_b,
    const float* __restrict__ l1_w, const float* __restrict__ l1_b,
    const float* __restrict__ l2_w, const float* __restrict__ l2_b,
    const float* __restrict__ g1, const float* __restrict__ b1,
    const float* __restrict__ g2, const float* __restrict__ b2,
    float* __restrict__ x_enc) {
  const int b = blockIdx.x;
  const int tid = threadIdx.x;
  const int s = tid >> 6, c = tid & 63;
  __shared__ float WbA[12288];        // 48KB: in_w, k-chunk f4 (ncol=192)
  __shared__ float WbB[12288];        // 48KB: out_w|l1_w|l2_w, k-chunk f4 (ncol=64)
  __shared__ float xx[TS][HID];
  __shared__ float qkv[TS][192];
  __shared__ float scb[400];
  __shared__ float tmpv[TS][HID];
  __shared__ float buf2[TS][HID];
  __shared__ float mu_s[TS], rs_s[TS];

  xx[s][c] = x0[b * 640 + tid];

  for (int l = 0; l < 2; l++) {
    const float* inw = in_w + l * HID * 192; const float* inb = in_b + l * 192;
    const float* ow  = out_w + l * HID * HID; const float* ob = out_b + l * HID;
    const float* w1  = l1_w + l * HID * HID; const float* bb1 = l1_b + l * HID;
    const float* w2  = l2_w + l * HID * HID; const float* bb2 = l2_b + l * HID;
    const float* gg1 = g1 + l * HID; const float* be1 = b1 + l * HID;
    const float* gg2 = g2 + l * HID; const float* be2 = b2 + l * HID;

    __syncthreads();   // xx ready / prev-layer reads of Wb done
    for (int i = tid; i < 12288; i += 640) {
      int k = i / 192, cc = i % 192;
      WbA[((k >> 2) * 192 + cc) * 4 + (k & 3)] = inw[i];
    }
    for (int i = tid; i < 12288; i += 640) {
      int m = i >> 12, rem = i & 4095, k = rem >> 6, cc = rem & 63;
      float v = (m == 0) ? ow[rem] : (m == 1) ? w1[rem] : w2[rem];
      WbB[m * 4096 + ((k >> 2) * 64 + cc) * 4 + (k & 3)] = v;
    }
    __syncthreads();

    // qkv = x @ in_w + in_b (1920 outputs, 3/thread)
    for (int o = tid; o < TS * 192; o += 640) {
      int ss = o / 192, cc = o % 192;
      float acc = inb[cc];
      #pragma unroll
      for (int k4 = 0; k4 < 16; k4++) {
        float4 w4 = *(const float4*)&WbA[(k4 * 192 + cc) * 4];
        float4 x4 = *(const float4*)&xx[ss][k4 * 4];
        ACC4(acc, x4, w4);
      }
      qkv[ss][cc] = acc;
    }
    __syncthreads();
    // scores
    if (tid < 400) {
      int h = tid / 100, r = (tid / 10) % 10, t = tid % 10;
      float acc = 0.0f;
      for (int d = 0; d < 16; d++) acc += qkv[r][h * 16 + d] * qkv[t][64 + h * 16 + d];
      scb[tid] = acc * 0.25f;
    }
    __syncthreads();
    // softmax over t
    if (tid < 40) {
      int base = (tid / 10) * 100 + (tid % 10) * 10;
      float m = -1e30f;
      for (int t = 0; t < 10; t++) m = fmaxf(m, scb[base + t]);
      float e[10], sum = 0.0f;
      for (int t = 0; t < 10; t++) { e[t] = expf(scb[base + t] - m); sum += e[t]; }
      float inv = 1.0f / sum;
      for (int t = 0; t < 10; t++) scb[base + t] = e[t] * inv;
    }
    __syncthreads();
    // o = att @ v
    {
      const int h = c >> 4;
      float acc = 0.0f;
      for (int t = 0; t < 10; t++) acc += scb[h * 100 + s * 10 + t] * qkv[t][128 + c];
      tmpv[s][c] = acc;
    }
    __syncthreads();
    // proj + residual (WbB m=0)
    {
      float acc = ob[c] + xx[s][c];
      #pragma unroll
      for (int k4 = 0; k4 < 16; k4++) {
        float4 w4 = *(const float4*)&WbB[(k4 * 64 + c) * 4];
        float4 x4 = *(const float4*)&tmpv[s][k4 * 4];
        ACC4(acc, x4, w4);
      }
      buf2[s][c] = acc;
    }
    __syncthreads();
    // LN1 stats (bitwise order)
    if (tid < 10) {
      float m = 0.0f;
      for (int cc = 0; cc < HID; cc++) m += buf2[tid][cc];
      m *= (1.0f / 64.0f);
      float v = 0.0f;
      for (int cc = 0; cc < HID; cc++) { float d = buf2[tid][cc] - m; v += d * d; }
      v *= (1.0f / 64.0f);
      mu_s[tid] = m; rs_s[tid] = rsqrtf(v + 1e-5f);
    }
    __syncthreads();
    xx[s][c] = (buf2[s][c] - mu_s[s]) * rs_s[s] * gg1[c] + be1[c];
    __syncthreads();
    // FF1 (WbB m=1)
    {
      float acc = bb1[c];
      #pragma unroll
      for (int k4 = 0; k4 < 16; k4++) {
        float4 w4 = *(const float4*)&WbB[4096 + (k4 * 64 + c) * 4];
        float4 x4 = *(const float4*)&xx[s][k4 * 4];
        ACC4(acc, x4, w4);
      }
      tmpv[s][c] = fmaxf(acc, 0.0f);
    }
    __syncthreads();
    // FF2 + residual (WbB m=2)
    {
      float acc = bb2[c] + xx[s][c];
      #pragma unroll
      for (int k4 = 0; k4 < 16; k4++) {
        float4 w4 = *(const float4*)&WbB[8192 + (k4 * 64 + c) * 4];
        float4 x4 = *(const float4*)&tmpv[s][k4 * 4];
        ACC4(acc, x4, w4);
      }
      buf2[s][c] = acc;
    }
    __syncthreads();
    // LN2 stats
    if (tid < 10) {
      float m = 0.0f;
      for (int cc = 0; cc < HID; cc++) m += buf2[tid][cc];
      m *= (1.0f / 64.0f);
      float v = 0.0f;
      for (int cc = 0; cc < HID; cc++) { float d = buf2[tid][cc] - m; v += d * d; }
      v *= (1.0f / 64.0f);
      mu_s[tid] = m; rs_s[tid] = rsqrtf(v + 1e-5f);
    }
    __syncthreads();
    xx[s][c] = (buf2[s][c] - mu_s[s]) * rs_s[s] * gg2[c] + be2[c];
  }
  __syncthreads();
  x_enc[b * 640 + tid] = xx[s][c];
}

// ---------------- wp2: x_inst / x_lag from x_enc (W chunks in LDS) -------------
__global__ __launch_bounds__(256) void wp2_kernel(
    const float* __restrict__ x_enc, const float* __restrict__ wp2,
    const float* __restrict__ bp2,
    float* __restrict__ x_inst, float* __restrict__ x_lag) {
  const int b = blockIdx.x >> 1, half = blockIdx.x & 1;
  const int tid = threadIdx.x;
  const int n = half * 256 + tid;
  __shared__ float xxl[640];
  __shared__ float Wb[32 * 256];   // 32KB
  for (int i = tid; i < 640; i += 256) xxl[i] = x_enc[b * 640 + i];
  float accs[10];
  #pragma unroll
  for (int si = 0; si < 10; si++) accs[si] = 0.0f;
  for (int ch = 0; ch < 2; ch++) {
    __syncthreads();
    for (int i = tid; i < 32 * 256; i += 256)
      Wb[i] = wp2[(ch * 32 + (i >> 8)) * NN + half * 256 + (i & 255)];
    __syncthreads();
    for (int k = 0; k < 32; k++) {
      float w = Wb[k * 256 + tid];
      #pragma unroll
      for (int si = 0; si < 10; si++) accs[si] += xxl[si * 64 + ch * 32 + k] * w;
    }
  }
  float bias = bp2[n];
  x_inst[b * NN + n] = accs[0] + bias;
  float lag = 0.0f;
  for (int si = 1; si < 10; si++) lag += accs[si];
  x_lag[b * NN + n] = lag * (1.0f / 9.0f) + bias;
}

// ---------------- adjacency: gram + gumbel + softmax + sigmoid -----------------
__global__ __launch_bounds__(256) void adj_kernel(
    const float* __restrict__ x_inst, const float* __restrict__ x_lag,
    const float* __restrict__ es_now, const float* __restrict__ es_lag,
    const float* __restrict__ prior, float* __restrict__ out) {
  const int k = blockIdx.x & 511;
  const int v = blockIdx.x >> 9;       // 0 = now, 1 = lag
  const int tid = threadIdx.x;
  const float* xs = v ? x_lag : x_inst;
  const float* es = v ? es_lag : es_now;
  __shared__ float ck[BAT];
  __shared__ float red[4];
  if (tid < BAT) ck[tid] = xs[tid * NN + k];
  __syncthreads();
  uint32_t ka, kb, t0, t1;
  threefry2x32(0u, 42u, 0u, (uint32_t)v, ka, kb);
  float vals[2];
  #pragma unroll
  for (int jj = 0; jj < 2; jj++) {
    int j = tid + jj * 256;
    float acc = 0.0f;
    for (int bb = 0; bb < BAT; bb++) acc += ck[bb] * xs[bb * NN + j];
    if (v) acc = sigmoidf_(acc);
    threefry2x32(ka, kb, 0u, (uint32_t)(k * NN + j), t0, t1);
    vals[jj] = acc + gumbel_bits(t0 ^ t1);
  }
  float m = block_red256(fmaxf(vals[0], vals[1]), red, true);
  float e0 = expf(vals[0] - m), e1 = expf(vals[1] - m);
  float s = block_red256(e0 + e1, red, false);
  float inv = 1.0f / s;
  #pragma unroll
  for (int jj = 0; jj < 2; jj++) {
    int j = tid + jj * 256;
    float a = (jj ? e1 : e0) * inv;
    float t = es[k * NN + j] + prior[k * NN + j] + a;
    float sg = sigmoidf_(t);
    sg = fminf(fmaxf(sg, 0.0f), 1.0f);
    if (j == k) sg = 0.0f;
    if (sg == 0.0f) sg = 1e-8f;
    out[v * NN * NN + k * NN + j] = sg;
  }
}

// ---------------- RealNVP flow ------------------------------------------------
__global__ __launch_bounds__(128) void flow_kernel(
    const float* __restrict__ Z, const float* __restrict__ fs_w, const float* __restrict__ fs_b,
    const float* __restrict__ ft_w, const float* __restrict__ ft_b, float* __restrict__ z2p) {
  const int n = blockIdx.x, c = threadIdx.x;
  __shared__ float z1[128];
  z1[c] = Z[n * LAT + c];
  __syncthreads();
  float a = fs_b[c], t = ft_b[c];
  for (int k = 0; k < 128; k++) {
    float zz = z1[k];
    a += zz * fs_w[k * 128 + c];
    t += zz * ft_w[k * 128 + c];
  }
  z2p[n * 128 + c] = sigmoidf_(a) * Z[n * LAT + 128 + c] + t;
}

// ---------------- gi table: only 100 distinct time values exist ----------------
__global__ __launch_bounds__(384) void gitab_kernel(
    const float* __restrict__ w_ih, const float* __restrict__ b_ih,
    float* __restrict__ gi_table) {
  const int v = blockIdx.x;      // 0..99
  const int t = threadIdx.x;     // col 0..383
  __shared__ float temb[256];
  if (t < 256) {
    float fr = (float)exp((double)(t & 127) * (10.0 / 127.0));  // np-style f64 -> f32
    float arg = (float)v * fr;
    temb[t] = (t < 128) ? sinf(arg) : cosf(arg);
  }
  __syncthreads();
  float acc = b_ih[t];
  for (int k = 0; k < 256; k++) acc += temb[k] * w_ih[k * 384 + t];
  gi_table[v * 384 + t] = acc;
}

// ------- w_hh transpose, k-chunk float4: out[(k4*384+t)*4 + (k&3)] = w_hh[k][t]
__global__ __launch_bounds__(256) void whht_kernel(
    const float* __restrict__ w_hh, float* __restrict__ w_hhT) {
  const int idx = blockIdx.x * 256 + threadIdx.x;   // 192 blocks, 49152 elems
  const int k4 = idx / 1536, rem = idx % 1536;
  const int t = rem >> 2, kl = rem & 3;
  w_hhT[idx] = w_hh[(k4 * 4 + kl) * 384 + t];
}

// ---------------- GRU: 2 nodes/block; whh reg-anchored via asm -----------------
__global__ __launch_bounds__(384, 2) void gru_kernel5(
    const int* __restrict__ tctx, const float* __restrict__ w_hhT,
    const float* __restrict__ b_hh, const float* __restrict__ gi_table,
    const float* __restrict__ tp_w, const float* __restrict__ tp_b,
    const float* __restrict__ z2p, float* __restrict__ z2f) {
  const int n0 = blockIdx.x * 2, t = threadIdx.x;
  __shared__ float h[2][128];
  __shared__ float sums[2][256];   // gi+gh for r,z cols
  __shared__ float ghn[2][128];    // gh for n cols
  __shared__ float gin[2][128];    // gi for n cols
  float4 whh[32];
  const float4* wt4 = (const float4*)w_hhT;
  #pragma unroll
  for (int k4 = 0; k4 < 32; k4++) whh[k4] = wt4[k4 * 384 + t];  // coalesced
  // Anchor whh in VGPRs: asm may modify -> rematerialization from memory illegal.
  #pragma unroll
  for (int k4 = 0; k4 < 32; k4++) {
    asm volatile("" : "+v"(whh[k4].x), "+v"(whh[k4].y),
                      "+v"(whh[k4].z), "+v"(whh[k4].w));
  }
  float gisA[10], gisB[10];
  #pragma unroll
  for (int s = 0; s < 10; s++) {
    gisA[s] = gi_table[tctx[n0 * 10 + s] * 384 + t];
    gisB[s] = gi_table[tctx[(n0 + 1) * 10 + s] * 384 + t];
  }
  float tpw[10];
  #pragma unroll
  for (int s = 0; s < 10; s++) tpw[s] = tp_w[s];
  const float bhh = b_hh[t];
  if (t < 256) h[t >> 7][t & 127] = 0.0f;
  float acc_tp = 0.0f;
  __syncthreads();
  #pragma unroll
  for (int s = 0; s < 10; s++) {
    float accA = bhh, accB = bhh;
    const float4* hA = (const float4*)h[0];
    const float4* hB = (const float4*)h[1];
    #pragma unroll
    for (int k4 = 0; k4 < 32; k4++) {
      float4 w4 = whh[k4];
      float4 a4 = hA[k4];
      float4 b4 = hB[k4];
      ACC4(accA, a4, w4);
      ACC4(accB, b4, w4);
    }
    if (t < 256) { sums[0][t] = gisA[s] + accA; sums[1][t] = gisB[s] + accB; }
    else {
      ghn[0][t - 256] = accA; gin[0][t - 256] = gisA[s];
      ghn[1][t - 256] = accB; gin[1][t - 256] = gisB[s];
    }
    __syncthreads();
    if (t < 256) {
      const int g = t >> 7, c = t & 127;
      float r = sigmoidf_(sums[g][c]);
      float z = sigmoidf_(sums[g][128 + c]);
      float nn2 = tanhf(gin[g][c] + r * ghn[g][c]);
      float hn = (1.0f - z) * nn2 + z * h[g][c];
      h[g][c] = hn;
      acc_tp += hn * tpw[s];
    }
    __syncthreads();
  }
  if (t < 256) {
    const int g = t >> 7, c = t & 127;
    z2f[(n0 + g) * 128 + c] = z2p[(n0 + g) * 128 + c] + acc_tp + tp_b[0];
  }
}

// ---------------- znA: zn_ws = concat(z1,z2f) @ ltn_w + b (4 nodes/block) ------
__global__ __launch_bounds__(256) void znA_kernel(
    const float* __restrict__ Z, const float* __restrict__ z2f,
    const float* __restrict__ ltn_w, const float* __restrict__ ltn_b,
    float* __restrict__ zn_ws) {
  const int nt = blockIdx.x >> 2, cg = blockIdx.x & 3;
  const int tid = threadIdx.x;
  const int oo = tid & 127, gsel = tid >> 7;
  const int o = cg * 128 + oo;
  const int n0 = nt * 4;
  __shared__ float zcat[4][LAT];   // 4KB
  for (int i = tid; i < 4 * LAT; i += 256) {
    int g = i >> 8, k = i & 255;
    zcat[g][k] = (k < 128) ? Z[(n0 + g) * LAT + k] : z2f[(n0 + g) * 128 + (k - 128)];
  }
  __syncthreads();
  const float bias = ltn_b[o];
  float accA = bias, accB = bias;
  const int g0 = gsel, g1 = gsel + 2;
  for (int k = 0; k < LAT; k++) {
    float w = ltn_w[k * NN + o];
    accA += zcat[g0][k] * w;
    accB += zcat[g1][k] * w;
  }
  zn_ws[(n0 + g0) * NN + o] = accA;
  zn_ws[(n0 + g1) * NN + o] = accB;
}

// ---------------- znB: xl/xr = zn_ws @ gat_w{l,r} + b (4 nodes/block) ----------
__global__ __launch_bounds__(256) void znB_kernel(
    const float* __restrict__ zn_ws,
    const float* __restrict__ wl, const float* __restrict__ bl,
    const float* __restrict__ wr, const float* __restrict__ br,
    float* __restrict__ xl, float* __restrict__ xr) {
  const int nt = blockIdx.x >> 2, cg = blockIdx.x & 3;
  const int tid = threadIdx.x;
  const int o = cg * 64 + (tid & 63), g = tid >> 6;
  const int n = nt * 4 + g;
  __shared__ float znr[4][NN];   // 8KB
  for (int i = tid; i < 4 * NN; i += 256)
    znr[i >> 9][i & 511] = zn_ws[(nt * 4 + (i >> 9)) * NN + (i & 511)];
  __syncthreads();
  float accL = bl[o], accR = br[o];
  for (int k = 0; k < NN; k++) {
    float z = znr[g][k];
    accL += z * wl[k * 256 + o];
    accR += z * wr[k * 256 + o];
  }
  xl[n * 256 + o] = accL;
  xr[n * 256 + o] = accR;
}

// ---------------- gatE2: e for (16 i) x (1 h) x (128 j) per block --------------
// grid 512 = it(32) x h(4) x jt(4). thread: cq = tid&15 (c-quad), il = tid>>4.
// xr4/aw4 in regs; xl read direct from L2 (cq-coalesced, il-broadcast);
// dot finished by 16-lane shfl_xor tree; staged via LDS, coalesced write.
__global__ __launch_bounds__(256) void gatE2_kernel(
    const float* __restrict__ xl, const float* __restrict__ xr,
    const float* __restrict__ attw, float* __restrict__ e_ws) {
  const int b = blockIdx.x;
  const int jt = b & 3, h = (b >> 2) & 3, it = b >> 4;
  const int tid = threadIdx.x;
  const int cq = tid & 15, il = tid >> 4;
  __shared__ float e_lds[16][132];
  const int i = it * 16 + il;
  const float4 xr4 = *(const float4*)&xr[i * 256 + h * 64 + cq * 4];
  const float4 aw4 = *(const float4*)&attw[h * 64 + cq * 4];
  #pragma unroll 4
  for (int jl = 0; jl < 128; jl++) {
    const int j = jt * 128 + jl;
    float4 v = *(const float4*)&xl[j * 256 + h * 64 + cq * 4];
    float a0 = xr4.x + v.x; a0 = (a0 >= 0.0f) ? a0 : 0.2f * a0;
    float a1 = xr4.y + v.y; a1 = (a1 >= 0.0f) ? a1 : 0.2f * a1;
    float a2 = xr4.z + v.z; a2 = (a2 >= 0.0f) ? a2 : 0.2f * a2;
    float a3 = xr4.w + v.w; a3 = (a3 >= 0.0f) ? a3 : 0.2f * a3;
    float s = a0 * aw4.x; s += a1 * aw4.y; s += a2 * aw4.z; s += a3 * aw4.w;
    s += __shfl_xor(s, 1, 64);
    s += __shfl_xor(s, 2, 64);
    s += __shfl_xor(s, 4, 64);
    s += __shfl_xor(s, 8, 64);
    if (cq == 0) e_lds[il][jl] = s;
  }
  __syncthreads();
  for (int o = tid; o < 16 * 128; o += 256) {
    int iw = o >> 7, jw = o & 127;
    e_ws[(it * 16 + iw) * 2048 + h * 512 + jt * 128 + jw] = e_lds[iw][jw];
  }
}

// ---------------- gatS: softmax over j per (i, h), in-place on e_ws ------------
__global__ __launch_bounds__(256) void gatS_kernel(float* __restrict__ e_ws) {
  const int i = blockIdx.x, tid = threadIdx.x;
  __shared__ float red[4];
  float* er = e_ws + i * 2048;
  for (int h = 0; h < 4; h++) {
    float v0 = er[h * 512 + tid], v1 = er[h * 512 + 256 + tid];
    float m = block_red256(fmaxf(v0, v1), red, true);
    float e0 = expf(v0 - m), e1 = expf(v1 - m);
    float s = block_red256(e0 + e1, red, false);
    float inv = 1.0f / s;
    er[h * 512 + tid] = e0 * inv;
    er[h * 512 + 256 + tid] = e1 * inv;
  }
}

// ---------------- gatX: x_emb = alpha @ xl + gbias -----------------------------
__global__ __launch_bounds__(256) void gatX_kernel(
    const float* __restrict__ e_ws, const float* __restrict__ xl,
    const float* __restrict__ gbias, float* __restrict__ xemb) {
  const int it = blockIdx.x >> 2, h = blockIdx.x & 3;
  const int tid = threadIdx.x;
  const int cq = tid & 15, jp = (tid >> 4) & 3, ip = tid >> 6;
  __shared__ float al[8][512];   // 16KB alpha rows for this head
  for (int i = tid; i < 8 * 512; i += 256)
    al[i >> 9][i & 511] = e_ws[(it * 8 + (i >> 9)) * 2048 + h * 512 + (i & 511)];
  __syncthreads();
  float acc[2][4];
  #pragma unroll
  for (int ii = 0; ii < 2; ii++)
    #pragma unroll
    for (int q = 0; q < 4; q++) acc[ii][q] = 0.0f;
  for (int js = 0; js < 128; js++) {
    const int j = js * 4 + jp;
    float4 x4 = *(const float4*)&xl[j * 256 + h * 64 + cq * 4];
    #pragma unroll
    for (int ii = 0; ii < 2; ii++) {
      float a = al[ip * 2 + ii][j];
      acc[ii][0] += a * x4.x; acc[ii][1] += a * x4.y;
      acc[ii][2] += a * x4.z; acc[ii][3] += a * x4.w;
    }
  }
  #pragma unroll
  for (int ii = 0; ii < 2; ii++)
    #pragma unroll
    for (int q = 0; q < 4; q++) {
      float v = acc[ii][q];
      v += __shfl_xor(v, 16, 64);
      v += __shfl_xor(v, 32, 64);
      acc[ii][q] = v;
    }
  if (jp == 0) {
    #pragma unroll
    for (int ii = 0; ii < 2; ii++) {
      const int i = it * 8 + ip * 2 + ii;
      const int o = h * 64 + cq * 4;
      float4 v = make_float4(acc[ii][0] + gbias[o],     acc[ii][1] + gbias[o + 1],
                             acc[ii][2] + gbias[o + 2], acc[ii][3] + gbias[o + 3]);
      *(float4*)&xemb[i * 256 + o] = v;
    }
  }
}

// ---------------- fallback fused GAT (2 targets/block) if ws too small ---------
__global__ __launch_bounds__(256) void gat_fused_kernel(
    const float* __restrict__ xl, const float* __restrict__ xr,
    const float* __restrict__ attw, const float* __restrict__ gbias,
    float* __restrict__ xemb) {
  const int i0 = blockIdx.x * 2, tid = threadIdx.x;
  __shared__ float xri[2][256];
  __shared__ float aw[256];
  __shared__ float e[2][4][NN];
  __shared__ float part[4][2][256];
  __shared__ float red[4];
  xri[0][tid] = xr[i0 * 256 + tid];
  xri[1][tid] = xr[(i0 + 1) * 256 + tid];
  aw[tid] = attw[tid];
  __syncthreads();
  #pragma unroll
  for (int jj = 0; jj < 2; jj++) {
    const int j = tid + jj * 256;
    const float4* xl4 = (const float4*)(xl + j * 256);
    #pragma unroll
    for (int hh = 0; hh < 4; hh++) {
      float accA = 0.0f, accB = 0.0f;
      #pragma unroll 4
      for (int c4 = 0; c4 < 16; c4++) {
        float4 v = xl4[hh * 16 + c4];
        const int cb = hh * 64 + c4 * 4;
        float w0 = aw[cb + 0], w1 = aw[cb + 1], w2 = aw[cb + 2], w3 = aw[cb + 3];
        float a0 = xri[0][cb + 0] + v.x; a0 = (a0 >= 0.0f) ? a0 : 0.2f * a0;
        float a1 = xri[0][cb + 1] + v.y; a1 = (a1 >= 0.0f) ? a1 : 0.2f * a1;
        float a2 = xri[0][cb + 2] + v.z; a2 = (a2 >= 0.0f) ? a2 : 0.2f * a2;
        float a3 = xri[0][cb + 3] + v.w; a3 = (a3 >= 0.0f) ? a3 : 0.2f * a3;
        accA += a0 * w0; accA += a1 * w1; accA += a2 * w2; accA += a3 * w3;
        float b0 = xri[1][cb + 0] + v.x; b0 = (b0 >= 0.0f) ? b0 : 0.2f * b0;
        float b1 = xri[1][cb + 1] + v.y; b1 = (b1 >= 0.0f) ? b1 : 0.2f * b1;
        float b2 = xri[1][cb + 2] + v.z; b2 = (b2 >= 0.0f) ? b2 : 0.2f * b2;
        float b3 = xri[1][cb + 3] + v.w; b3 = (b3 >= 0.0f) ? b3 : 0.2f * b3;
        accB += b0 * w0; accB += b1 * w1; accB += b2 * w2; accB += b3 * w3;
      }
      e[0][hh][j] = accA;
      e[1][hh][j] = accB;
    }
  }
  __syncthreads();
  for (int ii = 0; ii < 2; ii++) {
    for (int hh = 0; hh < 4; hh++) {
      float v0 = e[ii][hh][tid], v1 = e[ii][hh][tid + 256];
      float m = block_red256(fmaxf(v0, v1), red, true);
      float e0 = expf(v0 - m), e1 = expf(v1 - m);
      float ssum = block_red256(e0 + e1, red, false);
      float inv = 1.0f / ssum;
      e[ii][hh][tid] = e0 * inv;
      e[ii][hh][tid + 256] = e1 * inv;
    }
  }
  __syncthreads();
  {
    const int w = tid >> 6, lane = tid & 63;
    float a0 = 0.0f, a1 = 0.0f, a2 = 0.0f, a3 = 0.0f;
    float b0 = 0.0f, b1 = 0.0f, b2 = 0.0f, b3 = 0.0f;
    const int j0 = w * 128;
    for (int j = j0; j < j0 + 128; j++) {
      const float* xlr = xl + j * 256 + lane;
      float x0 = xlr[0], x1 = xlr[64], x2 = xlr[128], x3 = xlr[192];
      a0 += e[0][0][j] * x0; a1 += e[0][1][j] * x1;
      a2 += e[0][2][j] * x2; a3 += e[0][3][j] * x3;
      b0 += e[1][0][j] * x0; b1 += e[1][1][j] * x1;
      b2 += e[1][2][j] * x2; b3 += e[1][3][j] * x3;
    }
    part[w][0][lane]       = a0;
    part[w][0][64 + lane]  = a1;
    part[w][0][128 + lane] = a2;
    part[w][0][192 + lane] = a3;
    part[w][1][lane]       = b0;
    part[w][1][64 + lane]  = b1;
    part[w][1][128 + lane] = b2;
    part[w][1][192 + lane] = b3;
  }
  __syncthreads();
  {
    float accA = ((part[0][0][tid] + part[1][0][tid]) + part[2][0][tid]) + part[3][0][tid];
    float accB = ((part[0][1][tid] + part[1][1][tid]) + part[2][1][tid]) + part[3][1][tid];
    float gb = gbias[tid];
    xemb[i0 * 256 + tid] = accA + gb;
    xemb[(i0 + 1) * 256 + tid] = accB + gb;
  }
}

// ---------------- ml = x_emb @ gl_w + gl_b (tiled); mean/scale epilogue --------
__global__ __launch_bounds__(256) void glgemm_kernel(
    const float* __restrict__ xemb, const float* __restrict__ gl_w,
    const float* __restrict__ gl_b, float* __restrict__ out_mean,
    float* __restrict__ out_scale) {
  const int ct = blockIdx.x & 15, it = blockIdx.x >> 4;
  const int tid = threadIdx.x;
  const int i0 = it * 16, col = ct * 64 + (tid & 63), ti = tid >> 6;
  __shared__ float xe[16][LAT];   // 16KB
  for (int o = tid; o < 16 * LAT; o += 256) {
    xe[o >> 8][o & 255] = xemb[(i0 + (o >> 8)) * LAT + (o & 255)];
  }
  __syncthreads();
  const float bias = gl_b[col];
  float acc0 = bias, acc1 = bias, acc2 = bias, acc3 = bias;
  const int r0 = ti * 4;
  #pragma unroll 4
  for (int k = 0; k < LAT; k++) {
    float w = gl_w[k * 1024 + col];
    acc0 += xe[r0 + 0][k] * w;
    acc1 += xe[r0 + 1][k] * w;
    acc2 += xe[r0 + 2][k] * w;
    acc3 += xe[r0 + 3][k] * w;
  }
  float accs[4] = {acc0, acc1, acc2, acc3};
  if (col < 512) {
    #pragma unroll
    for (int q = 0; q < 4; q++) out_mean[(i0 + r0 + q) * NN + col] = accs[q];
  } else {
    #pragma unroll
    for (int q = 0; q < 4; q++) {
      float lv = fminf(fmaxf(accs[q], -5.0f), 2.0f);
      out_scale[(i0 + r0 + q) * NN + (col - 512)] = expf(0.5f * lv);
    }
  }
}

extern "C" void kernel_launch(void* const* d_in, const int* in_sizes, int n_in,
                              void* d_out, int out_size, void* d_ws, size_t ws_size,
                              hipStream_t stream) {
  (void)in_sizes; (void)n_in; (void)out_size;
  const float* X        = (const float*)d_in[0];
  const float* Z        = (const float*)d_in[1];
  const float* es_now   = (const float*)d_in[2];
  const float* es_lag   = (const float*)d_in[3];
  const float* prior    = (const float*)d_in[4];
  const float* wp1      = (const float*)d_in[5];
  const float* bp1      = (const float*)d_in[6];
  const float* enc_in_w = (const float*)d_in[7];
  const float* enc_in_b = (const float*)d_in[8];
  const float* enc_out_w= (const float*)d_in[9];
  const float* enc_out_b= (const float*)d_in[10];
  const float* enc_l1_w = (const float*)d_in[11];
  const float* enc_l1_b = (const float*)d_in[12];
  const float* enc_l2_w = (const float*)d_in[13];
  const float* enc_l2_b = (const float*)d_in[14];
  const float* enc_g1   = (const float*)d_in[15];
  const float* enc_b1   = (const float*)d_in[16];
  const float* enc_g2   = (const float*)d_in[17];
  const float* enc_b2   = (const float*)d_in[18];
  const float* wp2      = (const float*)d_in[19];
  const float* bp2      = (const float*)d_in[20];
  const float* fs_w     = (const float*)d_in[21];
  const float* fs_b     = (const float*)d_in[22];
  const float* ft_w     = (const float*)d_in[23];
  const float* ft_b     = (const float*)d_in[24];
  const float* gru_w_ih = (const float*)d_in[25];
  const float* gru_w_hh = (const float*)d_in[26];
  const float* gru_b_ih = (const float*)d_in[27];
  const float* gru_b_hh = (const float*)d_in[28];
  const float* tp_w     = (const float*)d_in[29];
  const float* tp_b     = (const float*)d_in[30];
  const float* ltn_w    = (const float*)d_in[31];
  const float* ltn_b    = (const float*)d_in[32];
  const float* gat_wl   = (const float*)d_in[33];
  const float* gat_bl   = (const float*)d_in[34];
  const float* gat_wr   = (const float*)d_in[35];
  const float* gat_br   = (const float*)d_in[36];
  const float* gat_att  = (const float*)d_in[37];
  const float* gat_bias = (const float*)d_in[38];
  const float* gl_w     = (const float*)d_in[39];
  const float* gl_b     = (const float*)d_in[40];
  const int*   tctx     = (const int*)d_in[41];

  float* out = (float*)d_out;
  float* ws  = (float*)d_ws;
  // ws layout (floats)
  float* x_inst   = ws;                // 64*512
  float* x_lag    = ws + 32768;        // 64*512
  float* z2p      = ws + 65536;        // 512*128
  float* z2f      = ws + 131072;       // 512*128
  float* xl       = ws + 196608;       // 512*256
  float* xr       = ws + 327680;       // 512*256
  float* gi_table = ws + 458752;       // 100*384
  float* xemb     = ws + 497152;       // 512*256
  float* x0       = ws + 628224;       // 640*64
  float* x_enc    = ws + 669184;       // 640*64
  float* zn_ws    = ws + 710144;       // 512*512
  float* e_ws     = ws + 972288;       // 512*2048 (4MB) — only if ws big enough
  float* w_hhT    = zn_ws;             // aliased; gru done before znA writes

  const bool big_ws = ws_size >= (size_t)(972288 + 512 * 2048) * 4;

  whht_kernel<<<dim3(192), dim3(256), 0, stream>>>(gru_w_hh, w_hhT);
  wp1_kernel<<<dim3(160), dim3(256), 0, stream>>>(X, wp1, bp1, x0);
  enc4_kernel<<<dim3(BAT), dim3(640), 0, stream>>>(
      x0, enc_in_w, enc_in_b, enc_out_w, enc_out_b,
      enc_l1_w, enc_l1_b, enc_l2_w, enc_l2_b,
      enc_g1, enc_b1, enc_g2, enc_b2, x_enc);
  wp2_kernel<<<dim3(128), dim3(256), 0, stream>>>(x_enc, wp2, bp2, x_inst, x_lag);
  adj_kernel<<<dim3(2 * NN), dim3(256), 0, stream>>>(
      x_inst, x_lag, es_now, es_lag, prior, out);
  gitab_kernel<<<dim3(100), dim3(384), 0, stream>>>(gru_w_ih, gru_b_ih, gi_table);
  flow_kernel<<<dim3(NN), dim3(128), 0, stream>>>(Z, fs_w, fs_b, ft_w, ft_b, z2p);
  gru_kernel5<<<dim3(NN / 2), dim3(384), 0, stream>>>(
      tctx, w_hhT, gru_b_hh, gi_table, tp_w, tp_b, z2p, z2f);
  znA_kernel<<<dim3(512), dim3(256), 0, stream>>>(Z, z2f, ltn_w, ltn_b, zn_ws);
  znB_kernel<<<dim3(512), dim3(256), 0, stream>>>(
      zn_ws, gat_wl, gat_bl, gat_wr, gat_br, xl, xr);
  if (big_ws) {
    gatE2_kernel<<<dim3(512), dim3(256), 0, stream>>>(xl, xr, gat_att, e_ws);
    gatS_kernel<<<dim3(NN), dim3(256), 0, stream>>>(e_ws);
    gatX_kernel<<<dim3(256), dim3(256), 0, stream>>>(e_ws, xl, gat_bias, xemb);
  } else {
    gat_fused_kernel<<<dim3(NN / 2), dim3(256), 0, stream>>>(
        xl, xr, gat_att, gat_bias, xemb);
  }
  glgemm_kernel<<<dim3(512), dim3(256), 0, stream>>>(
      xemb, gl_w, gl_b, out + 2 * NN * NN, out + 3 * NN * NN);
}

// Round 11
// 289.303 us; speedup vs baseline: 1.0658x; 1.0162x over previous
//
#include <hip/hip_runtime.h>
#include <stdint.h>
#include <math.h>

// Sizes
#define NN 512   // N_NODES
#define HID 64
#define LAT 256
#define TS 10
#define BAT 64

#define DEVFN static __device__ __forceinline__

DEVFN uint32_t rotl32(uint32_t v, int d) { return (v << d) | (v >> (32 - d)); }

// Threefry-2x32, 20 rounds (JAX threefry2x32_p). key=(k0,k1), count=(x0,x1).
DEVFN void threefry2x32(uint32_t k0, uint32_t k1, uint32_t x0, uint32_t x1,
                        uint32_t& o0, uint32_t& o1) {
  uint32_t ks0 = k0, ks1 = k1, ks2 = k0 ^ k1 ^ 0x1BD11BDAu;
  x0 += ks0; x1 += ks1;
  x0 += x1; x1 = rotl32(x1, 13); x1 ^= x0;
  x0 += x1; x1 = rotl32(x1, 15); x1 ^= x0;
  x0 += x1; x1 = rotl32(x1, 26); x1 ^= x0;
  x0 += x1; x1 = rotl32(x1, 6);  x1 ^= x0;
  x0 += ks1; x1 += ks2 + 1u;
  x0 += x1; x1 = rotl32(x1, 17); x1 ^= x0;
  x0 += x1; x1 = rotl32(x1, 29); x1 ^= x0;
  x0 += x1; x1 = rotl32(x1, 16); x1 ^= x0;
  x0 += x1; x1 = rotl32(x1, 24); x1 ^= x0;
  x0 += ks2; x1 += ks0 + 2u;
  x0 += x1; x1 = rotl32(x1, 13); x1 ^= x0;
  x0 += x1; x1 = rotl32(x1, 15); x1 ^= x0;
  x0 += x1; x1 = rotl32(x1, 26); x1 ^= x0;
  x0 += x1; x1 = rotl32(x1, 6);  x1 ^= x0;
  x0 += ks0; x1 += ks1 + 3u;
  x0 += x1; x1 = rotl32(x1, 17); x1 ^= x0;
  x0 += x1; x1 = rotl32(x1, 29); x1 ^= x0;
  x0 += x1; x1 = rotl32(x1, 16); x1 ^= x0;
  x0 += x1; x1 = rotl32(x1, 24); x1 ^= x0;
  x0 += ks1; x1 += ks2 + 4u;
  x0 += x1; x1 = rotl32(x1, 13); x1 ^= x0;
  x0 += x1; x1 = rotl32(x1, 15); x1 ^= x0;
  x0 += x1; x1 = rotl32(x1, 26); x1 ^= x0;
  x0 += x1; x1 = rotl32(x1, 6);  x1 ^= x0;
  x0 += ks2; x1 += ks0 + 5u;
  o0 = x0; o1 = x1;
}

DEVFN float sigmoidf_(float x) { return 1.0f / (1.0f + expf(-x)); }

// JAX gumbel from 32 random bits: uniform in [tiny, 1), g = -log(-log(u))
DEVFN float gumbel_bits(uint32_t bits) {
  const float tiny = 1.17549435e-38f;
  float f = __uint_as_float((bits >> 9) | 0x3F800000u) - 1.0f;
  float u = f * (1.0f - tiny) + tiny;
  u = fmaxf(tiny, u);
  return -logf(-logf(u));
}

// 256-thread block reduction (4 waves of 64)
DEVFN float block_red256(float v, float* red, bool ismax) {
  #pragma unroll
  for (int o = 32; o > 0; o >>= 1) {
    float w = __shfl_down(v, o, 64);
    v = ismax ? fmaxf(v, w) : v + w;
  }
  if ((threadIdx.x & 63) == 0) red[threadIdx.x >> 6] = v;
  __syncthreads();
  float r = ismax ? fmaxf(fmaxf(red[0], red[1]), fmaxf(red[2], red[3]))
                  : ((red[0] + red[1]) + (red[2] + red[3]));
  __syncthreads();
  return r;
}

// float4 dot-step, k-ascending order preserved
#define ACC4(acc, x4, w4) { acc += (x4).x * (w4).x; acc += (x4).y * (w4).y; \
                            acc += (x4).z * (w4).z; acc += (x4).w * (w4).w; }

// ---------------- wp1: x0 = X @ wp1 + bp1 (float4 k-chunk LDS) -----------------
__global__ __launch_bounds__(256) void wp1_kernel(
    const float* __restrict__ X, const float* __restrict__ wp1,
    const float* __restrict__ bp1, float* __restrict__ x0) {
  const int r0 = blockIdx.x * 4;
  const int tid = threadIdx.x, g = tid >> 6, c = tid & 63;
  __shared__ float Xb[4][NN];      // 8KB
  __shared__ float Wb[128 * 64];   // 32KB, k-chunk float4 layout
  for (int i = tid; i < 4 * NN; i += 256)
    Xb[i >> 9][i & 511] = X[r0 * NN + i];
  float acc = bp1[c];
  for (int ch = 0; ch < 4; ch++) {
    const int n0 = ch * 128;
    __syncthreads();
    for (int i = tid; i < 128 * 64; i += 256) {
      int k = i >> 6, cc = i & 63;
      Wb[((k >> 2) * 64 + cc) * 4 + (k & 3)] = wp1[(n0 + k) * 64 + cc];
    }
    __syncthreads();
    #pragma unroll 8
    for (int n4 = 0; n4 < 32; n4++) {
      float4 w4 = *(const float4*)&Wb[(n4 * 64 + c) * 4];
      float4 x4 = *(const float4*)&Xb[g][n0 + n4 * 4];
      ACC4(acc, x4, w4);
    }
  }
  x0[(r0 + g) * HID + c] = acc;
}

// ---------------- encoder layers: all weights LDS float4-staged per layer ------
__global__ __launch_bounds__(640) void enc4_kernel(
    const float* __restrict__ x0,
    const float* __restrict__ in_w, const float* __restrict__ in_b,
    const float* __restrict__ out_w, const float* __restrict__ out_b,
    const float* __restrict__ l1_w, const float* __restrict__ l1_b,
    const float* __restrict__ l2_w, const float* __restrict__ l2_b,
    const float* __restrict__ g1, const float* __restrict__ b1,
    const float* __restrict__ g2, const float* __restrict__ b2,
    float* __restrict__ x_enc) {
  const int b = blockIdx.x;
  const int tid = threadIdx.x;
  const int s = tid >> 6, c = tid & 63;
  __shared__ float WbA[12288];        // 48KB: in_w, k-chunk f4 (ncol=192)
  __shared__ float WbB[12288];        // 48KB: out_w|l1_w|l2_w, k-chunk f4 (ncol=64)
  __shared__ float xx[TS][HID];
  __shared__ float qkv[TS][192];
  __shared__ float scb[400];
  __shared__ float tmpv[TS][HID];
  __shared__ float buf2[TS][HID];
  __shared__ float mu_s[TS], rs_s[TS];

  xx[s][c] = x0[b * 640 + tid];

  for (int l = 0; l < 2; l++) {
    const float* inw = in_w + l * HID * 192; const float* inb = in_b + l * 192;
    const float* ow  = out_w + l * HID * HID; const float* ob = out_b + l * HID;
    const float* w1  = l1_w + l * HID * HID; const float* bb1 = l1_b + l * HID;
    const float* w2  = l2_w + l * HID * HID; const float* bb2 = l2_b + l * HID;
    const float* gg1 = g1 + l * HID; const float* be1 = b1 + l * HID;
    const float* gg2 = g2 + l * HID; const float* be2 = b2 + l * HID;

    __syncthreads();   // xx ready / prev-layer reads of Wb done
    for (int i = tid; i < 12288; i += 640) {
      int k = i / 192, cc = i % 192;
      WbA[((k >> 2) * 192 + cc) * 4 + (k & 3)] = inw[i];
    }
    for (int i = tid; i < 12288; i += 640) {
      int m = i >> 12, rem = i & 4095, k = rem >> 6, cc = rem & 63;
      float v = (m == 0) ? ow[rem] : (m == 1) ? w1[rem] : w2[rem];
      WbB[m * 4096 + ((k >> 2) * 64 + cc) * 4 + (k & 3)] = v;
    }
    __syncthreads();

    // qkv = x @ in_w + in_b (1920 outputs, 3/thread)
    for (int o = tid; o < TS * 192; o += 640) {
      int ss = o / 192, cc = o % 192;
      float acc = inb[cc];
      #pragma unroll
      for (int k4 = 0; k4 < 16; k4++) {
        float4 w4 = *(const float4*)&WbA[(k4 * 192 + cc) * 4];
        float4 x4 = *(const float4*)&xx[ss][k4 * 4];
        ACC4(acc, x4, w4);
      }
      qkv[ss][cc] = acc;
    }
    __syncthreads();
    // scores
    if (tid < 400) {
      int h = tid / 100, r = (tid / 10) % 10, t = tid % 10;
      float acc = 0.0f;
      for (int d = 0; d < 16; d++) acc += qkv[r][h * 16 + d] * qkv[t][64 + h * 16 + d];
      scb[tid] = acc * 0.25f;
    }
    __syncthreads();
    // softmax over t
    if (tid < 40) {
      int base = (tid / 10) * 100 + (tid % 10) * 10;
      float m = -1e30f;
      for (int t = 0; t < 10; t++) m = fmaxf(m, scb[base + t]);
      float e[10], sum = 0.0f;
      for (int t = 0; t < 10; t++) { e[t] = expf(scb[base + t] - m); sum += e[t]; }
      float inv = 1.0f / sum;
      for (int t = 0; t < 10; t++) scb[base + t] = e[t] * inv;
    }
    __syncthreads();
    // o = att @ v
    {
      const int h = c >> 4;
      float acc = 0.0f;
      for (int t = 0; t < 10; t++) acc += scb[h * 100 + s * 10 + t] * qkv[t][128 + c];
      tmpv[s][c] = acc;
    }
    __syncthreads();
    // proj + residual (WbB m=0)
    {
      float acc = ob[c] + xx[s][c];
      #pragma unroll
      for (int k4 = 0; k4 < 16; k4++) {
        float4 w4 = *(const float4*)&WbB[(k4 * 64 + c) * 4];
        float4 x4 = *(const float4*)&tmpv[s][k4 * 4];
        ACC4(acc, x4, w4);
      }
      buf2[s][c] = acc;
    }
    __syncthreads();
    // LN1 stats (bitwise order)
    if (tid < 10) {
      float m = 0.0f;
      for (int cc = 0; cc < HID; cc++) m += buf2[tid][cc];
      m *= (1.0f / 64.0f);
      float v = 0.0f;
      for (int cc = 0; cc < HID; cc++) { float d = buf2[tid][cc] - m; v += d * d; }
      v *= (1.0f / 64.0f);
      mu_s[tid] = m; rs_s[tid] = rsqrtf(v + 1e-5f);
    }
    __syncthreads();
    xx[s][c] = (buf2[s][c] - mu_s[s]) * rs_s[s] * gg1[c] + be1[c];
    __syncthreads();
    // FF1 (WbB m=1)
    {
      float acc = bb1[c];
      #pragma unroll
      for (int k4 = 0; k4 < 16; k4++) {
        float4 w4 = *(const float4*)&WbB[4096 + (k4 * 64 + c) * 4];
        float4 x4 = *(const float4*)&xx[s][k4 * 4];
        ACC4(acc, x4, w4);
      }
      tmpv[s][c] = fmaxf(acc, 0.0f);
    }
    __syncthreads();
    // FF2 + residual (WbB m=2)
    {
      float acc = bb2[c] + xx[s][c];
      #pragma unroll
      for (int k4 = 0; k4 < 16; k4++) {
        float4 w4 = *(const float4*)&WbB[8192 + (k4 * 64 + c) * 4];
        float4 x4 = *(const float4*)&tmpv[s][k4 * 4];
        ACC4(acc, x4, w4);
      }
      buf2[s][c] = acc;
    }
    __syncthreads();
    // LN2 stats
    if (tid < 10) {
      float m = 0.0f;
      for (int cc = 0; cc < HID; cc++) m += buf2[tid][cc];
      m *= (1.0f / 64.0f);
      float v = 0.0f;
      for (int cc = 0; cc < HID; cc++) { float d = buf2[tid][cc] - m; v += d * d; }
      v *= (1.0f / 64.0f);
      mu_s[tid] = m; rs_s[tid] = rsqrtf(v + 1e-5f);
    }
    __syncthreads();
    xx[s][c] = (buf2[s][c] - mu_s[s]) * rs_s[s] * gg2[c] + be2[c];
  }
  __syncthreads();
  x_enc[b * 640 + tid] = xx[s][c];
}

// ---------------- wp2: x_inst / x_lag from x_enc (W chunks in LDS) -------------
__global__ __launch_bounds__(256) void wp2_kernel(
    const float* __restrict__ x_enc, const float* __restrict__ wp2,
    const float* __restrict__ bp2,
    float* __restrict__ x_inst, float* __restrict__ x_lag) {
  const int b = blockIdx.x >> 1, half = blockIdx.x & 1;
  const int tid = threadIdx.x;
  const int n = half * 256 + tid;
  __shared__ float xxl[640];
  __shared__ float Wb[32 * 256];   // 32KB
  for (int i = tid; i < 640; i += 256) xxl[i] = x_enc[b * 640 + i];
  float accs[10];
  #pragma unroll
  for (int si = 0; si < 10; si++) accs[si] = 0.0f;
  for (int ch = 0; ch < 2; ch++) {
    __syncthreads();
    for (int i = tid; i < 32 * 256; i += 256)
      Wb[i] = wp2[(ch * 32 + (i >> 8)) * NN + half * 256 + (i & 255)];
    __syncthreads();
    for (int k = 0; k < 32; k++) {
      float w = Wb[k * 256 + tid];
      #pragma unroll
      for (int si = 0; si < 10; si++) accs[si] += xxl[si * 64 + ch * 32 + k] * w;
    }
  }
  float bias = bp2[n];
  x_inst[b * NN + n] = accs[0] + bias;
  float lag = 0.0f;
  for (int si = 1; si < 10; si++) lag += accs[si];
  x_lag[b * NN + n] = lag * (1.0f / 9.0f) + bias;
}

// ---------------- adjacency: gram + gumbel + softmax + sigmoid -----------------
__global__ __launch_bounds__(256) void adj_kernel(
    const float* __restrict__ x_inst, const float* __restrict__ x_lag,
    const float* __restrict__ es_now, const float* __restrict__ es_lag,
    const float* __restrict__ prior, float* __restrict__ out) {
  const int k = blockIdx.x & 511;
  const int v = blockIdx.x >> 9;       // 0 = now, 1 = lag
  const int tid = threadIdx.x;
  const float* xs = v ? x_lag : x_inst;
  const float* es = v ? es_lag : es_now;
  __shared__ float ck[BAT];
  __shared__ float red[4];
  if (tid < BAT) ck[tid] = xs[tid * NN + k];
  __syncthreads();
  uint32_t ka, kb, t0, t1;
  threefry2x32(0u, 42u, 0u, (uint32_t)v, ka, kb);
  float vals[2];
  #pragma unroll
  for (int jj = 0; jj < 2; jj++) {
    int j = tid + jj * 256;
    float acc = 0.0f;
    for (int bb = 0; bb < BAT; bb++) acc += ck[bb] * xs[bb * NN + j];
    if (v) acc = sigmoidf_(acc);
    threefry2x32(ka, kb, 0u, (uint32_t)(k * NN + j), t0, t1);
    vals[jj] = acc + gumbel_bits(t0 ^ t1);
  }
  float m = block_red256(fmaxf(vals[0], vals[1]), red, true);
  float e0 = expf(vals[0] - m), e1 = expf(vals[1] - m);
  float s = block_red256(e0 + e1, red, false);
  float inv = 1.0f / s;
  #pragma unroll
  for (int jj = 0; jj < 2; jj++) {
    int j = tid + jj * 256;
    float a = (jj ? e1 : e0) * inv;
    float t = es[k * NN + j] + prior[k * NN + j] + a;
    float sg = sigmoidf_(t);
    sg = fminf(fmaxf(sg, 0.0f), 1.0f);
    if (j == k) sg = 0.0f;
    if (sg == 0.0f) sg = 1e-8f;
    out[v * NN * NN + k * NN + j] = sg;
  }
}

// ---------------- RealNVP flow ------------------------------------------------
__global__ __launch_bounds__(128) void flow_kernel(
    const float* __restrict__ Z, const float* __restrict__ fs_w, const float* __restrict__ fs_b,
    const float* __restrict__ ft_w, const float* __restrict__ ft_b, float* __restrict__ z2p) {
  const int n = blockIdx.x, c = threadIdx.x;
  __shared__ float z1[128];
  z1[c] = Z[n * LAT + c];
  __syncthreads();
  float a = fs_b[c], t = ft_b[c];
  for (int k = 0; k < 128; k++) {
    float zz = z1[k];
    a += zz * fs_w[k * 128 + c];
    t += zz * ft_w[k * 128 + c];
  }
  z2p[n * 128 + c] = sigmoidf_(a) * Z[n * LAT + 128 + c] + t;
}

// ---------------- gi table: only 100 distinct time values exist ----------------
__global__ __launch_bounds__(384) void gitab_kernel(
    const float* __restrict__ w_ih, const float* __restrict__ b_ih,
    float* __restrict__ gi_table) {
  const int v = blockIdx.x;      // 0..99
  const int t = threadIdx.x;     // col 0..383
  __shared__ float temb[256];
  if (t < 256) {
    float fr = (float)exp((double)(t & 127) * (10.0 / 127.0));  // np-style f64 -> f32
    float arg = (float)v * fr;
    temb[t] = (t < 128) ? sinf(arg) : cosf(arg);
  }
  __syncthreads();
  float acc = b_ih[t];
  for (int k = 0; k < 256; k++) acc += temb[k] * w_ih[k * 384 + t];
  gi_table[v * 384 + t] = acc;
}

// ------- w_hh transpose, k-chunk float4: out[(k4*384+t)*4 + (k&3)] = w_hh[k][t]
__global__ __launch_bounds__(256) void whht_kernel(
    const float* __restrict__ w_hh, float* __restrict__ w_hhT) {
  const int idx = blockIdx.x * 256 + threadIdx.x;   // 192 blocks, 49152 elems
  const int k4 = idx / 1536, rem = idx % 1536;
  const int t = rem >> 2, kl = rem & 3;
  w_hhT[idx] = w_hh[(k4 * 4 + kl) * 384 + t];
}

// ---------------- GRU: 1 node/block, 768 threads, 2-way k-split ----------------
// thread (c = tid%384, half = tid/384) holds 16 float4 of w_hhT (64 VGPRs) —
// small enough that no budget spills it. Partials combined via LDS.
__global__ __launch_bounds__(768, 1) void gru_kernel6(
    const int* __restrict__ tctx, const float* __restrict__ w_hhT,
    const float* __restrict__ b_hh, const float* __restrict__ gi_table,
    const float* __restrict__ tp_w, const float* __restrict__ tp_b,
    const float* __restrict__ z2p, float* __restrict__ z2f) {
  const int n = blockIdx.x, tid = threadIdx.x;
  const int half = tid >= 384 ? 1 : 0;
  const int c = tid - half * 384;
  __shared__ float h[128];
  __shared__ float part[2][384];
  float4 whh[16];
  const float4* wt4 = (const float4*)w_hhT;
  #pragma unroll
  for (int k4 = 0; k4 < 16; k4++)
    whh[k4] = wt4[(half * 16 + k4) * 384 + c];   // consecutive c -> coalesced
  #pragma unroll
  for (int k4 = 0; k4 < 16; k4++) {
    asm volatile("" : "+v"(whh[k4].x), "+v"(whh[k4].y),
                      "+v"(whh[k4].z), "+v"(whh[k4].w));
  }
  const float bhh = (half == 0) ? b_hh[c] : 0.0f;
  float acc_tp = 0.0f;
  if (tid < 128) h[tid] = 0.0f;
  __syncthreads();
  #pragma unroll
  for (int s = 0; s < 10; s++) {
    float acc = bhh;
    const float4* h4 = (const float4*)h;
    #pragma unroll
    for (int k4 = 0; k4 < 16; k4++) {
      float4 hv = h4[half * 16 + k4];
      ACC4(acc, hv, whh[k4]);
    }
    part[half][c] = acc;
    __syncthreads();
    if (tid < 128) {
      const int v = tctx[n * 10 + s];
      const float* gi = gi_table + v * 384;
      float gh_r = part[0][tid]       + part[1][tid];
      float gh_z = part[0][128 + tid] + part[1][128 + tid];
      float gh_n = part[0][256 + tid] + part[1][256 + tid];
      float r = sigmoidf_(gi[tid] + gh_r);
      float z = sigmoidf_(gi[128 + tid] + gh_z);
      float nn2 = tanhf(gi[256 + tid] + r * gh_n);
      float hn = (1.0f - z) * nn2 + z * h[tid];
      h[tid] = hn;
      acc_tp += hn * tp_w[s];
    }
    __syncthreads();
  }
  if (tid < 128) z2f[n * 128 + tid] = z2p[n * 128 + tid] + acc_tp + tp_b[0];
}

// ---------------- znA: zn_ws = concat(z1,z2f) @ ltn_w + b (4 nodes/block) ------
__global__ __launch_bounds__(256) void znA_kernel(
    const float* __restrict__ Z, const float* __restrict__ z2f,
    const float* __restrict__ ltn_w, const float* __restrict__ ltn_b,
    float* __restrict__ zn_ws) {
  const int nt = blockIdx.x >> 2, cg = blockIdx.x & 3;
  const int tid = threadIdx.x;
  const int oo = tid & 127, gsel = tid >> 7;
  const int o = cg * 128 + oo;
  const int n0 = nt * 4;
  __shared__ float zcat[4][LAT];   // 4KB
  for (int i = tid; i < 4 * LAT; i += 256) {
    int g = i >> 8, k = i & 255;
    zcat[g][k] = (k < 128) ? Z[(n0 + g) * LAT + k] : z2f[(n0 + g) * 128 + (k - 128)];
  }
  __syncthreads();
  const float bias = ltn_b[o];
  float accA = bias, accB = bias;
  const int g0 = gsel, g1 = gsel + 2;
  for (int k = 0; k < LAT; k++) {
    float w = ltn_w[k * NN + o];
    accA += zcat[g0][k] * w;
    accB += zcat[g1][k] * w;
  }
  zn_ws[(n0 + g0) * NN + o] = accA;
  zn_ws[(n0 + g1) * NN + o] = accB;
}

// ---------------- znB: xl/xr = zn_ws @ gat_w{l,r} + b (4 nodes/block) ----------
__global__ __launch_bounds__(256) void znB_kernel(
    const float* __restrict__ zn_ws,
    const float* __restrict__ wl, const float* __restrict__ bl,
    const float* __restrict__ wr, const float* __restrict__ br,
    float* __restrict__ xl, float* __restrict__ xr) {
  const int nt = blockIdx.x >> 2, cg = blockIdx.x & 3;
  const int tid = threadIdx.x;
  const int o = cg * 64 + (tid & 63), g = tid >> 6;
  const int n = nt * 4 + g;
  __shared__ float znr[4][NN];   // 8KB
  for (int i = tid; i < 4 * NN; i += 256)
    znr[i >> 9][i & 511] = zn_ws[(nt * 4 + (i >> 9)) * NN + (i & 511)];
  __syncthreads();
  float accL = bl[o], accR = br[o];
  for (int k = 0; k < NN; k++) {
    float z = znr[g][k];
    accL += z * wl[k * 256 + o];
    accR += z * wr[k * 256 + o];
  }
  xl[n * 256 + o] = accL;
  xr[n * 256 + o] = accR;
}

// ---------------- gatE3: e tile 32i x 128j x 1h per block, LDS operands --------
// grid 256 = it(16) x h(4) x jt(4). thread: ig=tid>>5 (4 i), jg=tid&31 (4 j,
// strided by 32). No cross-lane ops; c-ascending dot in registers.
__global__ __launch_bounds__(256) void gatE3_kernel(
    const float* __restrict__ xl, const float* __restrict__ xr,
    const float* __restrict__ attw, float* __restrict__ e_ws) {
  const int b = blockIdx.x;
  const int jt = b & 3, h = (b >> 2) & 3, it = b >> 4;
  const int tid = threadIdx.x;
  const int ig = tid >> 5, jg = tid & 31;
  __shared__ float xlt[8192];   // 32KB: [c4 16][j 128][4]
  __shared__ float xrt[2048];   // 8KB:  [c4 16][i 32][4]
  __shared__ float awl[64];
  for (int idx = tid; idx < 2048; idx += 256) {
    int j = idx >> 4, c4 = idx & 15;
    float4 v = *(const float4*)&xl[(jt * 128 + j) * 256 + h * 64 + c4 * 4];
    *(float4*)&xlt[(c4 * 128 + j) * 4] = v;
  }
  for (int idx = tid; idx < 512; idx += 256) {
    int i = idx >> 4, c4 = idx & 15;
    float4 v = *(const float4*)&xr[(it * 32 + i) * 256 + h * 64 + c4 * 4];
    *(float4*)&xrt[(c4 * 32 + i) * 4] = v;
  }
  if (tid < 64) awl[tid] = attw[h * 64 + tid];
  __syncthreads();
  float acc[4][4];
  #pragma unroll
  for (int iq = 0; iq < 4; iq++)
    #pragma unroll
    for (int q = 0; q < 4; q++) acc[iq][q] = 0.0f;
  #pragma unroll
  for (int c4 = 0; c4 < 16; c4++) {
    float4 aw4 = *(const float4*)&awl[c4 * 4];
    float4 xr4[4], xl4[4];
    #pragma unroll
    for (int iq = 0; iq < 4; iq++)
      xr4[iq] = *(const float4*)&xrt[(c4 * 32 + ig * 4 + iq) * 4];
    #pragma unroll
    for (int q = 0; q < 4; q++)
      xl4[q] = *(const float4*)&xlt[(c4 * 128 + jg + q * 32) * 4];
    #pragma unroll
    for (int iq = 0; iq < 4; iq++) {
      #pragma unroll
      for (int q = 0; q < 4; q++) {
        float a0 = xr4[iq].x + xl4[q].x; a0 = (a0 >= 0.0f) ? a0 : 0.2f * a0;
        float a1 = xr4[iq].y + xl4[q].y; a1 = (a1 >= 0.0f) ? a1 : 0.2f * a1;
        float a2 = xr4[iq].z + xl4[q].z; a2 = (a2 >= 0.0f) ? a2 : 0.2f * a2;
        float a3 = xr4[iq].w + xl4[q].w; a3 = (a3 >= 0.0f) ? a3 : 0.2f * a3;
        float sv = acc[iq][q];
        sv += a0 * aw4.x; sv += a1 * aw4.y; sv += a2 * aw4.z; sv += a3 * aw4.w;
        acc[iq][q] = sv;
      }
    }
  }
  #pragma unroll
  for (int iq = 0; iq < 4; iq++) {
    const int i = it * 32 + ig * 4 + iq;
    #pragma unroll
    for (int q = 0; q < 4; q++)
      e_ws[i * 2048 + h * 512 + jt * 128 + jg + q * 32] = acc[iq][q];
  }
}

// ---------------- gatS: softmax over j per (i, h), in-place on e_ws ------------
__global__ __launch_bounds__(256) void gatS_kernel(float* __restrict__ e_ws) {
  const int i = blockIdx.x, tid = threadIdx.x;
  __shared__ float red[4];
  float* er = e_ws + i * 2048;
  for (int h = 0; h < 4; h++) {
    float v0 = er[h * 512 + tid], v1 = er[h * 512 + 256 + tid];
    float m = block_red256(fmaxf(v0, v1), red, true);
    float e0 = expf(v0 - m), e1 = expf(v1 - m);
    float s = block_red256(e0 + e1, red, false);
    float inv = 1.0f / s;
    er[h * 512 + tid] = e0 * inv;
    er[h * 512 + 256 + tid] = e1 * inv;
  }
}

// ---------------- gatX: x_emb = alpha @ xl + gbias -----------------------------
__global__ __launch_bounds__(256) void gatX_kernel(
    const float* __restrict__ e_ws, const float* __restrict__ xl,
    const float* __restrict__ gbias, float* __restrict__ xemb) {
  const int it = blockIdx.x >> 2, h = blockIdx.x & 3;
  const int tid = threadIdx.x;
  const int cq = tid & 15, jp = (tid >> 4) & 3, ip = tid >> 6;
  __shared__ float al[8][512];   // 16KB alpha rows for this head
  for (int i = tid; i < 8 * 512; i += 256)
    al[i >> 9][i & 511] = e_ws[(it * 8 + (i >> 9)) * 2048 + h * 512 + (i & 511)];
  __syncthreads();
  float acc[2][4];
  #pragma unroll
  for (int ii = 0; ii < 2; ii++)
    #pragma unroll
    for (int q = 0; q < 4; q++) acc[ii][q] = 0.0f;
  for (int js = 0; js < 128; js++) {
    const int j = js * 4 + jp;
    float4 x4 = *(const float4*)&xl[j * 256 + h * 64 + cq * 4];
    #pragma unroll
    for (int ii = 0; ii < 2; ii++) {
      float a = al[ip * 2 + ii][j];
      acc[ii][0] += a * x4.x; acc[ii][1] += a * x4.y;
      acc[ii][2] += a * x4.z; acc[ii][3] += a * x4.w;
    }
  }
  #pragma unroll
  for (int ii = 0; ii < 2; ii++)
    #pragma unroll
    for (int q = 0; q < 4; q++) {
      float v = acc[ii][q];
      v += __shfl_xor(v, 16, 64);
      v += __shfl_xor(v, 32, 64);
      acc[ii][q] = v;
    }
  if (jp == 0) {
    #pragma unroll
    for (int ii = 0; ii < 2; ii++) {
      const int i = it * 8 + ip * 2 + ii;
      const int o = h * 64 + cq * 4;
      float4 v = make_float4(acc[ii][0] + gbias[o],     acc[ii][1] + gbias[o + 1],
                             acc[ii][2] + gbias[o + 2], acc[ii][3] + gbias[o + 3]);
      *(float4*)&xemb[i * 256 + o] = v;
    }
  }
}

// ---------------- fallback fused GAT (2 targets/block) if ws too small ---------
__global__ __launch_bounds__(256) void gat_fused_kernel(
    const float* __restrict__ xl, const float* __restrict__ xr,
    const float* __restrict__ attw, const float* __restrict__ gbias,
    float* __restrict__ xemb) {
  const int i0 = blockIdx.x * 2, tid = threadIdx.x;
  __shared__ float xri[2][256];
  __shared__ float aw[256];
  __shared__ float e[2][4][NN];
  __shared__ float part[4][2][256];
  __shared__ float red[4];
  xri[0][tid] = xr[i0 * 256 + tid];
  xri[1][tid] = xr[(i0 + 1) * 256 + tid];
  aw[tid] = attw[tid];
  __syncthreads();
  #pragma unroll
  for (int jj = 0; jj < 2; jj++) {
    const int j = tid + jj * 256;
    const float4* xl4 = (const float4*)(xl + j * 256);
    #pragma unroll
    for (int hh = 0; hh < 4; hh++) {
      float accA = 0.0f, accB = 0.0f;
      #pragma unroll 4
      for (int c4 = 0; c4 < 16; c4++) {
        float4 v = xl4[hh * 16 + c4];
        const int cb = hh * 64 + c4 * 4;
        float w0 = aw[cb + 0], w1 = aw[cb + 1], w2 = aw[cb + 2], w3 = aw[cb + 3];
        float a0 = xri[0][cb + 0] + v.x; a0 = (a0 >= 0.0f) ? a0 : 0.2f * a0;
        float a1 = xri[0][cb + 1] + v.y; a1 = (a1 >= 0.0f) ? a1 : 0.2f * a1;
        float a2 = xri[0][cb + 2] + v.z; a2 = (a2 >= 0.0f) ? a2 : 0.2f * a2;
        float a3 = xri[0][cb + 3] + v.w; a3 = (a3 >= 0.0f) ? a3 : 0.2f * a3;
        accA += a0 * w0; accA += a1 * w1; accA += a2 * w2; accA += a3 * w3;
        float b0 = xri[1][cb + 0] + v.x; b0 = (b0 >= 0.0f) ? b0 : 0.2f * b0;
        float b1 = xri[1][cb + 1] + v.y; b1 = (b1 >= 0.0f) ? b1 : 0.2f * b1;
        float b2 = xri[1][cb + 2] + v.z; b2 = (b2 >= 0.0f) ? b2 : 0.2f * b2;
        float b3 = xri[1][cb + 3] + v.w; b3 = (b3 >= 0.0f) ? b3 : 0.2f * b3;
        accB += b0 * w0; accB += b1 * w1; accB += b2 * w2; accB += b3 * w3;
      }
      e[0][hh][j] = accA;
      e[1][hh][j] = accB;
    }
  }
  __syncthreads();
  for (int ii = 0; ii < 2; ii++) {
    for (int hh = 0; hh < 4; hh++) {
      float v0 = e[ii][hh][tid], v1 = e[ii][hh][tid + 256];
      float m = block_red256(fmaxf(v0, v1), red, true);
      float e0 = expf(v0 - m), e1 = expf(v1 - m);
      float ssum = block_red256(e0 + e1, red, false);
      float inv = 1.0f / ssum;
      e[ii][hh][tid] = e0 * inv;
      e[ii][hh][tid + 256] = e1 * inv;
    }
  }
  __syncthreads();
  {
    const int w = tid >> 6, lane = tid & 63;
    float a0 = 0.0f, a1 = 0.0f, a2 = 0.0f, a3 = 0.0f;
    float b0 = 0.0f, b1 = 0.0f, b2 = 0.0f, b3 = 0.0f;
    const int j0 = w * 128;
    for (int j = j0; j < j0 + 128; j++) {
      const float* xlr = xl + j * 256 + lane;
      float x0 = xlr[0], x1 = xlr[64], x2 = xlr[128], x3 = xlr[192];
      a0 += e[0][0][j] * x0; a1 += e[0][1][j] * x1;
      a2 += e[0][2][j] * x2; a3 += e[0][3][j] * x3;
      b0 += e[1][0][j] * x0; b1 += e[1][1][j] * x1;
      b2 += e[1][2][j] * x2; b3 += e[1][3][j] * x3;
    }
    part[w][0][lane]       = a0;
    part[w][0][64 + lane]  = a1;
    part[w][0][128 + lane] = a2;
    part[w][0][192 + lane] = a3;
    part[w][1][lane]       = b0;
    part[w][1][64 + lane]  = b1;
    part[w][1][128 + lane] = b2;
    part[w][1][192 + lane] = b3;
  }
  __syncthreads();
  {
    float accA = ((part[0][0][tid] + part[1][0][tid]) + part[2][0][tid]) + part[3][0][tid];
    float accB = ((part[0][1][tid] + part[1][1][tid]) + part[2][1][tid]) + part[3][1][tid];
    float gb = gbias[tid];
    xemb[i0 * 256 + tid] = accA + gb;
    xemb[(i0 + 1) * 256 + tid] = accB + gb;
  }
}

// ---------------- ml = x_emb @ gl_w + gl_b (tiled); mean/scale epilogue --------
__global__ __launch_bounds__(256) void glgemm_kernel(
    const float* __restrict__ xemb, const float* __restrict__ gl_w,
    const float* __restrict__ gl_b, float* __restrict__ out_mean,
    float* __restrict__ out_scale) {
  const int ct = blockIdx.x & 15, it = blockIdx.x >> 4;
  const int tid = threadIdx.x;
  const int i0 = it * 16, col = ct * 64 + (tid & 63), ti = tid >> 6;
  __shared__ float xe[16][LAT];   // 16KB
  for (int o = tid; o < 16 * LAT; o += 256) {
    xe[o >> 8][o & 255] = xemb[(i0 + (o >> 8)) * LAT + (o & 255)];
  }
  __syncthreads();
  const float bias = gl_b[col];
  float acc0 = bias, acc1 = bias, acc2 = bias, acc3 = bias;
  const int r0 = ti * 4;
  #pragma unroll 4
  for (int k = 0; k < LAT; k++) {
    float w = gl_w[k * 1024 + col];
    acc0 += xe[r0 + 0][k] * w;
    acc1 += xe[r0 + 1][k] * w;
    acc2 += xe[r0 + 2][k] * w;
    acc3 += xe[r0 + 3][k] * w;
  }
  float accs[4] = {acc0, acc1, acc2, acc3};
  if (col < 512) {
    #pragma unroll
    for (int q = 0; q < 4; q++) out_mean[(i0 + r0 + q) * NN + col] = accs[q];
  } else {
    #pragma unroll
    for (int q = 0; q < 4; q++) {
      float lv = fminf(fmaxf(accs[q], -5.0f), 2.0f);
      out_scale[(i0 + r0 + q) * NN + (col - 512)] = expf(0.5f * lv);
    }
  }
}

extern "C" void kernel_launch(void* const* d_in, const int* in_sizes, int n_in,
                              void* d_out, int out_size, void* d_ws, size_t ws_size,
                              hipStream_t stream) {
  (void)in_sizes; (void)n_in; (void)out_size;
  const float* X        = (const float*)d_in[0];
  const float* Z        = (const float*)d_in[1];
  const float* es_now   = (const float*)d_in[2];
  const float* es_lag   = (const float*)d_in[3];
  const float* prior    = (const float*)d_in[4];
  const float* wp1      = (const float*)d_in[5];
  const float* bp1      = (const float*)d_in[6];
  const float* enc_in_w = (const float*)d_in[7];
  const float* enc_in_b = (const float*)d_in[8];
  const float* enc_out_w= (const float*)d_in[9];
  const float* enc_out_b= (const float*)d_in[10];
  const float* enc_l1_w = (const float*)d_in[11];
  const float* enc_l1_b = (const float*)d_in[12];
  const float* enc_l2_w = (const float*)d_in[13];
  const float* enc_l2_b = (const float*)d_in[14];
  const float* enc_g1   = (const float*)d_in[15];
  const float* enc_b1   = (const float*)d_in[16];
  const float* enc_g2   = (const float*)d_in[17];
  const float* enc_b2   = (const float*)d_in[18];
  const float* wp2      = (const float*)d_in[19];
  const float* bp2      = (const float*)d_in[20];
  const float* fs_w     = (const float*)d_in[21];
  const float* fs_b     = (const float*)d_in[22];
  const float* ft_w     = (const float*)d_in[23];
  const float* ft_b     = (const float*)d_in[24];
  const float* gru_w_ih = (const float*)d_in[25];
  const float* gru_w_hh = (const float*)d_in[26];
  const float* gru_b_ih = (const float*)d_in[27];
  const float* gru_b_hh = (const float*)d_in[28];
  const float* tp_w     = (const float*)d_in[29];
  const float* tp_b     = (const float*)d_in[30];
  const float* ltn_w    = (const float*)d_in[31];
  const float* ltn_b    = (const float*)d_in[32];
  const float* gat_wl   = (const float*)d_in[33];
  const float* gat_bl   = (const float*)d_in[34];
  const float* gat_wr   = (const float*)d_in[35];
  const float* gat_br   = (const float*)d_in[36];
  const float* gat_att  = (const float*)d_in[37];
  const float* gat_bias = (const float*)d_in[38];
  const float* gl_w     = (const float*)d_in[39];
  const float* gl_b     = (const float*)d_in[40];
  const int*   tctx     = (const int*)d_in[41];

  float* out = (float*)d_out;
  float* ws  = (float*)d_ws;
  // ws layout (floats)
  float* x_inst   = ws;                // 64*512
  float* x_lag    = ws + 32768;        // 64*512
  float* z2p      = ws + 65536;        // 512*128
  float* z2f      = ws + 131072;       // 512*128
  float* xl       = ws + 196608;       // 512*256
  float* xr       = ws + 327680;       // 512*256
  float* gi_table = ws + 458752;       // 100*384
  float* xemb     = ws + 497152;       // 512*256
  float* x0       = ws + 628224;       // 640*64
  float* x_enc    = ws + 669184;       // 640*64
  float* zn_ws    = ws + 710144;       // 512*512
  float* e_ws     = ws + 972288;       // 512*2048 (4MB) — only if ws big enough
  float* w_hhT    = zn_ws;             // aliased; gru done before znA writes

  const bool big_ws = ws_size >= (size_t)(972288 + 512 * 2048) * 4;

  whht_kernel<<<dim3(192), dim3(256), 0, stream>>>(gru_w_hh, w_hhT);
  wp1_kernel<<<dim3(160), dim3(256), 0, stream>>>(X, wp1, bp1, x0);
  enc4_kernel<<<dim3(BAT), dim3(640), 0, stream>>>(
      x0, enc_in_w, enc_in_b, enc_out_w, enc_out_b,
      enc_l1_w, enc_l1_b, enc_l2_w, enc_l2_b,
      enc_g1, enc_b1, enc_g2, enc_b2, x_enc);
  wp2_kernel<<<dim3(128), dim3(256), 0, stream>>>(x_enc, wp2, bp2, x_inst, x_lag);
  adj_kernel<<<dim3(2 * NN), dim3(256), 0, stream>>>(
      x_inst, x_lag, es_now, es_lag, prior, out);
  gitab_kernel<<<dim3(100), dim3(384), 0, stream>>>(gru_w_ih, gru_b_ih, gi_table);
  flow_kernel<<<dim3(NN), dim3(128), 0, stream>>>(Z, fs_w, fs_b, ft_w, ft_b, z2p);
  gru_kernel6<<<dim3(NN), dim3(768), 0, stream>>>(
      tctx, w_hhT, gru_b_hh, gi_table, tp_w, tp_b, z2p, z2f);
  znA_kernel<<<dim3(512), dim3(256), 0, stream>>>(Z, z2f, ltn_w, ltn_b, zn_ws);
  znB_kernel<<<dim3(512), dim3(256), 0, stream>>>(
      zn_ws, gat_wl, gat_bl, gat_wr, gat_br, xl, xr);
  if (big_ws) {
    gatE3_kernel<<<dim3(256), dim3(256), 0, stream>>>(xl, xr, gat_att, e_ws);
    gatS_kernel<<<dim3(NN), dim3(256), 0, stream>>>(e_ws);
    gatX_kernel<<<dim3(256), dim3(256), 0, stream>>>(e_ws, xl, gat_bias, xemb);
  } else {
    gat_fused_kernel<<<dim3(NN / 2), dim3(256), 0, stream>>>(
        xl, xr, gat_att, gat_bias, xemb);
  }
  glgemm_kernel<<<dim3(512), dim3(256), 0, stream>>>(
      xemb, gl_w, gl_b, out + 2 * NN * NN, out + 3 * NN * NN);
}

// Round 12
// 213.503 us; speedup vs baseline: 1.4442x; 1.3550x over previous
//
#include <hip/hip_runtime.h>
#include <stdint.h>
#include <math.h>

// Sizes
#define NN 512   // N_NODES
#define HID 64
#define LAT 256
#define TS 10
#define BAT 64

#define DEVFN static __device__ __forceinline__

DEVFN uint32_t rotl32(uint32_t v, int d) { return (v << d) | (v >> (32 - d)); }

// Threefry-2x32, 20 rounds (JAX threefry2x32_p). key=(k0,k1), count=(x0,x1).
DEVFN void threefry2x32(uint32_t k0, uint32_t k1, uint32_t x0, uint32_t x1,
                        uint32_t& o0, uint32_t& o1) {
  uint32_t ks0 = k0, ks1 = k1, ks2 = k0 ^ k1 ^ 0x1BD11BDAu;
  x0 += ks0; x1 += ks1;
  x0 += x1; x1 = rotl32(x1, 13); x1 ^= x0;
  x0 += x1; x1 = rotl32(x1, 15); x1 ^= x0;
  x0 += x1; x1 = rotl32(x1, 26); x1 ^= x0;
  x0 += x1; x1 = rotl32(x1, 6);  x1 ^= x0;
  x0 += ks1; x1 += ks2 + 1u;
  x0 += x1; x1 = rotl32(x1, 17); x1 ^= x0;
  x0 += x1; x1 = rotl32(x1, 29); x1 ^= x0;
  x0 += x1; x1 = rotl32(x1, 16); x1 ^= x0;
  x0 += x1; x1 = rotl32(x1, 24); x1 ^= x0;
  x0 += ks2; x1 += ks0 + 2u;
  x0 += x1; x1 = rotl32(x1, 13); x1 ^= x0;
  x0 += x1; x1 = rotl32(x1, 15); x1 ^= x0;
  x0 += x1; x1 = rotl32(x1, 26); x1 ^= x0;
  x0 += x1; x1 = rotl32(x1, 6);  x1 ^= x0;
  x0 += ks0; x1 += ks1 + 3u;
  x0 += x1; x1 = rotl32(x1, 17); x1 ^= x0;
  x0 += x1; x1 = rotl32(x1, 29); x1 ^= x0;
  x0 += x1; x1 = rotl32(x1, 16); x1 ^= x0;
  x0 += x1; x1 = rotl32(x1, 24); x1 ^= x0;
  x0 += ks1; x1 += ks2 + 4u;
  x0 += x1; x1 = rotl32(x1, 13); x1 ^= x0;
  x0 += x1; x1 = rotl32(x1, 15); x1 ^= x0;
  x0 += x1; x1 = rotl32(x1, 26); x1 ^= x0;
  x0 += x1; x1 = rotl32(x1, 6);  x1 ^= x0;
  x0 += ks2; x1 += ks0 + 5u;
  o0 = x0; o1 = x1;
}

DEVFN float sigmoidf_(float x) { return 1.0f / (1.0f + expf(-x)); }

// JAX gumbel from 32 random bits: uniform in [tiny, 1), g = -log(-log(u))
DEVFN float gumbel_bits(uint32_t bits) {
  const float tiny = 1.17549435e-38f;
  float f = __uint_as_float((bits >> 9) | 0x3F800000u) - 1.0f;
  float u = f * (1.0f - tiny) + tiny;
  u = fmaxf(tiny, u);
  return -logf(-logf(u));
}

// 256-thread block reduction (4 waves of 64)
DEVFN float block_red256(float v, float* red, bool ismax) {
  #pragma unroll
  for (int o = 32; o > 0; o >>= 1) {
    float w = __shfl_down(v, o, 64);
    v = ismax ? fmaxf(v, w) : v + w;
  }
  if ((threadIdx.x & 63) == 0) red[threadIdx.x >> 6] = v;
  __syncthreads();
  float r = ismax ? fmaxf(fmaxf(red[0], red[1]), fmaxf(red[2], red[3]))
                  : ((red[0] + red[1]) + (red[2] + red[3]));
  __syncthreads();
  return r;
}

// float4 dot-step, k-ascending order preserved
#define ACC4(acc, x4, w4) { acc += (x4).x * (w4).x; acc += (x4).y * (w4).y; \
                            acc += (x4).z * (w4).z; acc += (x4).w * (w4).w; }

// ---------------- wp1: x0 = X @ wp1 + bp1 (float4 k-chunk LDS) -----------------
__global__ __launch_bounds__(256) void wp1_kernel(
    const float* __restrict__ X, const float* __restrict__ wp1,
    const float* __restrict__ bp1, float* __restrict__ x0) {
  const int r0 = blockIdx.x * 4;
  const int tid = threadIdx.x, g = tid >> 6, c = tid & 63;
  __shared__ float Xb[4][NN];      // 8KB
  __shared__ float Wb[128 * 64];   // 32KB, k-chunk float4 layout
  for (int i = tid; i < 4 * NN; i += 256)
    Xb[i >> 9][i & 511] = X[r0 * NN + i];
  float acc = bp1[c];
  for (int ch = 0; ch < 4; ch++) {
    const int n0 = ch * 128;
    __syncthreads();
    for (int i = tid; i < 128 * 64; i += 256) {
      int k = i >> 6, cc = i & 63;
      Wb[((k >> 2) * 64 + cc) * 4 + (k & 3)] = wp1[(n0 + k) * 64 + cc];
    }
    __syncthreads();
    #pragma unroll 8
    for (int n4 = 0; n4 < 32; n4++) {
      float4 w4 = *(const float4*)&Wb[(n4 * 64 + c) * 4];
      float4 x4 = *(const float4*)&Xb[g][n0 + n4 * 4];
      ACC4(acc, x4, w4);
    }
  }
  x0[(r0 + g) * HID + c] = acc;
}

// ---------------- encoder layers: all weights LDS float4-staged per layer ------
__global__ __launch_bounds__(640) void enc4_kernel(
    const float* __restrict__ x0,
    const float* __restrict__ in_w, const float* __restrict__ in_b,
    const float* __restrict__ out_w, const float* __restrict__ out_b,
    const float* __restrict__ l1_w, const float* __restrict__ l1_b,
    const float* __restrict__ l2_w, const float* __restrict__ l2_b,
    const float* __restrict__ g1, const float* __restrict__ b1,
    const float* __restrict__ g2, const float* __restrict__ b2,
    float* __restrict__ x_enc) {
  const int b = blockIdx.x;
  const int tid = threadIdx.x;
  const int s = tid >> 6, c = tid & 63;
  __shared__ float WbA[12288];        // 48KB: in_w, k-chunk f4 (ncol=192)
  __shared__ float WbB[12288];        // 48KB: out_w|l1_w|l2_w, k-chunk f4 (ncol=64)
  __shared__ float xx[TS][HID];
  __shared__ float qkv[TS][192];
  __shared__ float scb[400];
  __shared__ float tmpv[TS][HID];
  __shared__ float buf2[TS][HID];
  __shared__ float mu_s[TS], rs_s[TS];

  xx[s][c] = x0[b * 640 + tid];

  for (int l = 0; l < 2; l++) {
    const float* inw = in_w + l * HID * 192; const float* inb = in_b + l * 192;
    const float* ow  = out_w + l * HID * HID; const float* ob = out_b + l * HID;
    const float* w1  = l1_w + l * HID * HID; const float* bb1 = l1_b + l * HID;
    const float* w2  = l2_w + l * HID * HID; const float* bb2 = l2_b + l * HID;
    const float* gg1 = g1 + l * HID; const float* be1 = b1 + l * HID;
    const float* gg2 = g2 + l * HID; const float* be2 = b2 + l * HID;

    __syncthreads();   // xx ready / prev-layer reads of Wb done
    for (int i = tid; i < 12288; i += 640) {
      int k = i / 192, cc = i % 192;
      WbA[((k >> 2) * 192 + cc) * 4 + (k & 3)] = inw[i];
    }
    for (int i = tid; i < 12288; i += 640) {
      int m = i >> 12, rem = i & 4095, k = rem >> 6, cc = rem & 63;
      float v = (m == 0) ? ow[rem] : (m == 1) ? w1[rem] : w2[rem];
      WbB[m * 4096 + ((k >> 2) * 64 + cc) * 4 + (k & 3)] = v;
    }
    __syncthreads();

    // qkv = x @ in_w + in_b (1920 outputs, 3/thread)
    for (int o = tid; o < TS * 192; o += 640) {
      int ss = o / 192, cc = o % 192;
      float acc = inb[cc];
      #pragma unroll
      for (int k4 = 0; k4 < 16; k4++) {
        float4 w4 = *(const float4*)&WbA[(k4 * 192 + cc) * 4];
        float4 x4 = *(const float4*)&xx[ss][k4 * 4];
        ACC4(acc, x4, w4);
      }
      qkv[ss][cc] = acc;
    }
    __syncthreads();
    // scores
    if (tid < 400) {
      int h = tid / 100, r = (tid / 10) % 10, t = tid % 10;
      float acc = 0.0f;
      for (int d = 0; d < 16; d++) acc += qkv[r][h * 16 + d] * qkv[t][64 + h * 16 + d];
      scb[tid] = acc * 0.25f;
    }
    __syncthreads();
    // softmax over t
    if (tid < 40) {
      int base = (tid / 10) * 100 + (tid % 10) * 10;
      float m = -1e30f;
      for (int t = 0; t < 10; t++) m = fmaxf(m, scb[base + t]);
      float e[10], sum = 0.0f;
      for (int t = 0; t < 10; t++) { e[t] = expf(scb[base + t] - m); sum += e[t]; }
      float inv = 1.0f / sum;
      for (int t = 0; t < 10; t++) scb[base + t] = e[t] * inv;
    }
    __syncthreads();
    // o = att @ v
    {
      const int h = c >> 4;
      float acc = 0.0f;
      for (int t = 0; t < 10; t++) acc += scb[h * 100 + s * 10 + t] * qkv[t][128 + c];
      tmpv[s][c] = acc;
    }
    __syncthreads();
    // proj + residual (WbB m=0)
    {
      float acc = ob[c] + xx[s][c];
      #pragma unroll
      for (int k4 = 0; k4 < 16; k4++) {
        float4 w4 = *(const float4*)&WbB[(k4 * 64 + c) * 4];
        float4 x4 = *(const float4*)&tmpv[s][k4 * 4];
        ACC4(acc, x4, w4);
      }
      buf2[s][c] = acc;
    }
    __syncthreads();
    // LN1 stats (bitwise order)
    if (tid < 10) {
      float m = 0.0f;
      for (int cc = 0; cc < HID; cc++) m += buf2[tid][cc];
      m *= (1.0f / 64.0f);
      float v = 0.0f;
      for (int cc = 0; cc < HID; cc++) { float d = buf2[tid][cc] - m; v += d * d; }
      v *= (1.0f / 64.0f);
      mu_s[tid] = m; rs_s[tid] = rsqrtf(v + 1e-5f);
    }
    __syncthreads();
    xx[s][c] = (buf2[s][c] - mu_s[s]) * rs_s[s] * gg1[c] + be1[c];
    __syncthreads();
    // FF1 (WbB m=1)
    {
      float acc = bb1[c];
      #pragma unroll
      for (int k4 = 0; k4 < 16; k4++) {
        float4 w4 = *(const float4*)&WbB[4096 + (k4 * 64 + c) * 4];
        float4 x4 = *(const float4*)&xx[s][k4 * 4];
        ACC4(acc, x4, w4);
      }
      tmpv[s][c] = fmaxf(acc, 0.0f);
    }
    __syncthreads();
    // FF2 + residual (WbB m=2)
    {
      float acc = bb2[c] + xx[s][c];
      #pragma unroll
      for (int k4 = 0; k4 < 16; k4++) {
        float4 w4 = *(const float4*)&WbB[8192 + (k4 * 64 + c) * 4];
        float4 x4 = *(const float4*)&tmpv[s][k4 * 4];
        ACC4(acc, x4, w4);
      }
      buf2[s][c] = acc;
    }
    __syncthreads();
    // LN2 stats
    if (tid < 10) {
      float m = 0.0f;
      for (int cc = 0; cc < HID; cc++) m += buf2[tid][cc];
      m *= (1.0f / 64.0f);
      float v = 0.0f;
      for (int cc = 0; cc < HID; cc++) { float d = buf2[tid][cc] - m; v += d * d; }
      v *= (1.0f / 64.0f);
      mu_s[tid] = m; rs_s[tid] = rsqrtf(v + 1e-5f);
    }
    __syncthreads();
    xx[s][c] = (buf2[s][c] - mu_s[s]) * rs_s[s] * gg2[c] + be2[c];
  }
  __syncthreads();
  x_enc[b * 640 + tid] = xx[s][c];
}

// ---------------- wp2: x_inst / x_lag from x_enc (W chunks in LDS) -------------
__global__ __launch_bounds__(256) void wp2_kernel(
    const float* __restrict__ x_enc, const float* __restrict__ wp2,
    const float* __restrict__ bp2,
    float* __restrict__ x_inst, float* __restrict__ x_lag) {
  const int b = blockIdx.x >> 1, half = blockIdx.x & 1;
  const int tid = threadIdx.x;
  const int n = half * 256 + tid;
  __shared__ float xxl[640];
  __shared__ float Wb[32 * 256];   // 32KB
  for (int i = tid; i < 640; i += 256) xxl[i] = x_enc[b * 640 + i];
  float accs[10];
  #pragma unroll
  for (int si = 0; si < 10; si++) accs[si] = 0.0f;
  for (int ch = 0; ch < 2; ch++) {
    __syncthreads();
    for (int i = tid; i < 32 * 256; i += 256)
      Wb[i] = wp2[(ch * 32 + (i >> 8)) * NN + half * 256 + (i & 255)];
    __syncthreads();
    for (int k = 0; k < 32; k++) {
      float w = Wb[k * 256 + tid];
      #pragma unroll
      for (int si = 0; si < 10; si++) accs[si] += xxl[si * 64 + ch * 32 + k] * w;
    }
  }
  float bias = bp2[n];
  x_inst[b * NN + n] = accs[0] + bias;
  float lag = 0.0f;
  for (int si = 1; si < 10; si++) lag += accs[si];
  x_lag[b * NN + n] = lag * (1.0f / 9.0f) + bias;
}

// ---------------- adjacency: gram + gumbel + softmax + sigmoid -----------------
__global__ __launch_bounds__(256) void adj_kernel(
    const float* __restrict__ x_inst, const float* __restrict__ x_lag,
    const float* __restrict__ es_now, const float* __restrict__ es_lag,
    const float* __restrict__ prior, float* __restrict__ out) {
  const int k = blockIdx.x & 511;
  const int v = blockIdx.x >> 9;       // 0 = now, 1 = lag
  const int tid = threadIdx.x;
  const float* xs = v ? x_lag : x_inst;
  const float* es = v ? es_lag : es_now;
  __shared__ float ck[BAT];
  __shared__ float red[4];
  if (tid < BAT) ck[tid] = xs[tid * NN + k];
  __syncthreads();
  uint32_t ka, kb, t0, t1;
  threefry2x32(0u, 42u, 0u, (uint32_t)v, ka, kb);
  float vals[2];
  #pragma unroll
  for (int jj = 0; jj < 2; jj++) {
    int j = tid + jj * 256;
    float acc = 0.0f;
    for (int bb = 0; bb < BAT; bb++) acc += ck[bb] * xs[bb * NN + j];
    if (v) acc = sigmoidf_(acc);
    threefry2x32(ka, kb, 0u, (uint32_t)(k * NN + j), t0, t1);
    vals[jj] = acc + gumbel_bits(t0 ^ t1);
  }
  float m = block_red256(fmaxf(vals[0], vals[1]), red, true);
  float e0 = expf(vals[0] - m), e1 = expf(vals[1] - m);
  float s = block_red256(e0 + e1, red, false);
  float inv = 1.0f / s;
  #pragma unroll
  for (int jj = 0; jj < 2; jj++) {
    int j = tid + jj * 256;
    float a = (jj ? e1 : e0) * inv;
    float t = es[k * NN + j] + prior[k * NN + j] + a;
    float sg = sigmoidf_(t);
    sg = fminf(fmaxf(sg, 0.0f), 1.0f);
    if (j == k) sg = 0.0f;
    if (sg == 0.0f) sg = 1e-8f;
    out[v * NN * NN + k * NN + j] = sg;
  }
}

// ---------------- RealNVP flow ------------------------------------------------
__global__ __launch_bounds__(128) void flow_kernel(
    const float* __restrict__ Z, const float* __restrict__ fs_w, const float* __restrict__ fs_b,
    const float* __restrict__ ft_w, const float* __restrict__ ft_b, float* __restrict__ z2p) {
  const int n = blockIdx.x, c = threadIdx.x;
  __shared__ float z1[128];
  z1[c] = Z[n * LAT + c];
  __syncthreads();
  float a = fs_b[c], t = ft_b[c];
  for (int k = 0; k < 128; k++) {
    float zz = z1[k];
    a += zz * fs_w[k * 128 + c];
    t += zz * ft_w[k * 128 + c];
  }
  z2p[n * 128 + c] = sigmoidf_(a) * Z[n * LAT + 128 + c] + t;
}

// ---------------- gi table: only 100 distinct time values exist ----------------
__global__ __launch_bounds__(384) void gitab_kernel(
    const float* __restrict__ w_ih, const float* __restrict__ b_ih,
    float* __restrict__ gi_table) {
  const int v = blockIdx.x;      // 0..99
  const int t = threadIdx.x;     // col 0..383
  __shared__ float temb[256];
  if (t < 256) {
    float fr = (float)exp((double)(t & 127) * (10.0 / 127.0));  // np-style f64 -> f32
    float arg = (float)v * fr;
    temb[t] = (t < 128) ? sinf(arg) : cosf(arg);
  }
  __syncthreads();
  float acc = b_ih[t];
  for (int k = 0; k < 256; k++) acc += temb[k] * w_ih[k * 384 + t];
  gi_table[v * 384 + t] = acc;
}

// ------- w_hh transpose, k-chunk float4: out[(k4*384+t)*4 + (k&3)] = w_hh[k][t]
__global__ __launch_bounds__(256) void whht_kernel(
    const float* __restrict__ w_hh, float* __restrict__ w_hhT) {
  const int idx = blockIdx.x * 256 + threadIdx.x;   // 192 blocks, 49152 elems
  const int k4 = idx / 1536, rem = idx % 1536;
  const int t = rem >> 2, kl = rem & 3;
  w_hhT[idx] = w_hh[(k4 * 4 + kl) * 384 + t];
}

// ---------------- GRU: 1 node/block, 768 threads, 2-way k-split ----------------
__global__ __launch_bounds__(768, 1) void gru_kernel6(
    const int* __restrict__ tctx, const float* __restrict__ w_hhT,
    const float* __restrict__ b_hh, const float* __restrict__ gi_table,
    const float* __restrict__ tp_w, const float* __restrict__ tp_b,
    const float* __restrict__ z2p, float* __restrict__ z2f) {
  const int n = blockIdx.x, tid = threadIdx.x;
  const int half = tid >= 384 ? 1 : 0;
  const int c = tid - half * 384;
  __shared__ float h[128];
  __shared__ float part[2][384];
  float4 whh[16];
  const float4* wt4 = (const float4*)w_hhT;
  #pragma unroll
  for (int k4 = 0; k4 < 16; k4++)
    whh[k4] = wt4[(half * 16 + k4) * 384 + c];   // consecutive c -> coalesced
  #pragma unroll
  for (int k4 = 0; k4 < 16; k4++) {
    asm volatile("" : "+v"(whh[k4].x), "+v"(whh[k4].y),
                      "+v"(whh[k4].z), "+v"(whh[k4].w));
  }
  const float bhh = (half == 0) ? b_hh[c] : 0.0f;
  float acc_tp = 0.0f;
  if (tid < 128) h[tid] = 0.0f;
  __syncthreads();
  #pragma unroll
  for (int s = 0; s < 10; s++) {
    float acc = bhh;
    const float4* h4 = (const float4*)h;
    #pragma unroll
    for (int k4 = 0; k4 < 16; k4++) {
      float4 hv = h4[half * 16 + k4];
      ACC4(acc, hv, whh[k4]);
    }
    part[half][c] = acc;
    __syncthreads();
    if (tid < 128) {
      const int v = tctx[n * 10 + s];
      const float* gi = gi_table + v * 384;
      float gh_r = part[0][tid]       + part[1][tid];
      float gh_z = part[0][128 + tid] + part[1][128 + tid];
      float gh_n = part[0][256 + tid] + part[1][256 + tid];
      float r = sigmoidf_(gi[tid] + gh_r);
      float z = sigmoidf_(gi[128 + tid] + gh_z);
      float nn2 = tanhf(gi[256 + tid] + r * gh_n);
      float hn = (1.0f - z) * nn2 + z * h[tid];
      h[tid] = hn;
      acc_tp += hn * tp_w[s];
    }
    __syncthreads();
  }
  if (tid < 128) z2f[n * 128 + tid] = z2p[n * 128 + tid] + acc_tp + tp_b[0];
}

// ---------------- znA: zn_ws = concat(z1,z2f) @ ltn_w + b (4 nodes/block) ------
__global__ __launch_bounds__(256) void znA_kernel(
    const float* __restrict__ Z, const float* __restrict__ z2f,
    const float* __restrict__ ltn_w, const float* __restrict__ ltn_b,
    float* __restrict__ zn_ws) {
  const int nt = blockIdx.x >> 2, cg = blockIdx.x & 3;
  const int tid = threadIdx.x;
  const int oo = tid & 127, gsel = tid >> 7;
  const int o = cg * 128 + oo;
  const int n0 = nt * 4;
  __shared__ float zcat[4][LAT];   // 4KB
  for (int i = tid; i < 4 * LAT; i += 256) {
    int g = i >> 8, k = i & 255;
    zcat[g][k] = (k < 128) ? Z[(n0 + g) * LAT + k] : z2f[(n0 + g) * 128 + (k - 128)];
  }
  __syncthreads();
  const float bias = ltn_b[o];
  float accA = bias, accB = bias;
  const int g0 = gsel, g1 = gsel + 2;
  for (int k = 0; k < LAT; k++) {
    float w = ltn_w[k * NN + o];
    accA += zcat[g0][k] * w;
    accB += zcat[g1][k] * w;
  }
  zn_ws[(n0 + g0) * NN + o] = accA;
  zn_ws[(n0 + g1) * NN + o] = accB;
}

// ---------------- znB: xl/xr = zn_ws @ gat_w{l,r} + b (4 nodes/block) ----------
__global__ __launch_bounds__(256) void znB_kernel(
    const float* __restrict__ zn_ws,
    const float* __restrict__ wl, const float* __restrict__ bl,
    const float* __restrict__ wr, const float* __restrict__ br,
    float* __restrict__ xl, float* __restrict__ xr) {
  const int nt = blockIdx.x >> 2, cg = blockIdx.x & 3;
  const int tid = threadIdx.x;
  const int o = cg * 64 + (tid & 63), g = tid >> 6;
  const int n = nt * 4 + g;
  __shared__ float znr[4][NN];   // 8KB
  for (int i = tid; i < 4 * NN; i += 256)
    znr[i >> 9][i & 511] = zn_ws[(nt * 4 + (i >> 9)) * NN + (i & 511)];
  __syncthreads();
  float accL = bl[o], accR = br[o];
  for (int k = 0; k < NN; k++) {
    float z = znr[g][k];
    accL += z * wl[k * 256 + o];
    accR += z * wr[k * 256 + o];
  }
  xl[n * 256 + o] = accL;
  xr[n * 256 + o] = accR;
}

// ---------------- gatE4: e tile 16i x 64j x 1h; grid 1024 for 4 blocks/CU ------
// thread: i = tid>>4 group... mapping: il = tid>>4 is NOT used; see below.
// lanes: i = tid >> 4 (16 i, wave-local 4), jq = tid & 15 (16 j-quads -> 64 j).
// xlt transposed [c][68-pad j] (2-way reads), xrt [16][68] (conflict-free),
// aw4 uniform. Per c4: 6 LDS + 48 VALU. c-ascending single-chain acc.
__global__ __launch_bounds__(256) void gatE4_kernel(
    const float* __restrict__ xl, const float* __restrict__ xr,
    const float* __restrict__ attw, float* __restrict__ e_ws) {
  const int b = blockIdx.x;
  const int jt = b & 7, h = (b >> 3) & 3, it = b >> 5;
  const int tid = threadIdx.x;
  const int i_l = tid >> 4, jq = tid & 15;
  __shared__ float xlt[64][68];   // 17KB  [c][j] padded
  __shared__ float xrt[16][68];   // 4.25KB [i][c] padded
  __shared__ float awl[64];
  // stage xl tile transposed: idx -> (j = idx>>4, c4 = idx&15)
  for (int idx = tid; idx < 1024; idx += 256) {
    int j = idx >> 4, c4 = idx & 15;
    float4 v = *(const float4*)&xl[(jt * 64 + j) * 256 + h * 64 + c4 * 4];
    xlt[c4 * 4 + 0][j] = v.x;
    xlt[c4 * 4 + 1][j] = v.y;
    xlt[c4 * 4 + 2][j] = v.z;
    xlt[c4 * 4 + 3][j] = v.w;
  }
  // stage xr tile [i][c]
  for (int idx = tid; idx < 1024; idx += 256) {
    int i = idx >> 6, cc = idx & 63;
    xrt[i][cc] = xr[(it * 16 + i) * 256 + h * 64 + cc];
  }
  if (tid < 64) awl[tid] = attw[h * 64 + tid];
  __syncthreads();
  float acc0 = 0.0f, acc1 = 0.0f, acc2 = 0.0f, acc3 = 0.0f;
  #pragma unroll
  for (int c4 = 0; c4 < 16; c4++) {
    float4 aw4 = *(const float4*)&awl[c4 * 4];
    float4 xr4 = *(const float4*)&xrt[i_l][c4 * 4];
    float4 xl0 = *(const float4*)&xlt[c4 * 4 + 0][jq * 4];
    float4 xl1 = *(const float4*)&xlt[c4 * 4 + 1][jq * 4];
    float4 xl2 = *(const float4*)&xlt[c4 * 4 + 2][jq * 4];
    float4 xl3 = *(const float4*)&xlt[c4 * 4 + 3][jq * 4];
    // c = c4*4+0
    {
      float v0 = xr4.x + xl0.x; v0 = (v0 >= 0.0f) ? v0 : 0.2f * v0;
      float v1 = xr4.x + xl0.y; v1 = (v1 >= 0.0f) ? v1 : 0.2f * v1;
      float v2 = xr4.x + xl0.z; v2 = (v2 >= 0.0f) ? v2 : 0.2f * v2;
      float v3 = xr4.x + xl0.w; v3 = (v3 >= 0.0f) ? v3 : 0.2f * v3;
      acc0 += v0 * aw4.x; acc1 += v1 * aw4.x; acc2 += v2 * aw4.x; acc3 += v3 * aw4.x;
    }
    // c = c4*4+1
    {
      float v0 = xr4.y + xl1.x; v0 = (v0 >= 0.0f) ? v0 : 0.2f * v0;
      float v1 = xr4.y + xl1.y; v1 = (v1 >= 0.0f) ? v1 : 0.2f * v1;
      float v2 = xr4.y + xl1.z; v2 = (v2 >= 0.0f) ? v2 : 0.2f * v2;
      float v3 = xr4.y + xl1.w; v3 = (v3 >= 0.0f) ? v3 : 0.2f * v3;
      acc0 += v0 * aw4.y; acc1 += v1 * aw4.y; acc2 += v2 * aw4.y; acc3 += v3 * aw4.y;
    }
    // c = c4*4+2
    {
      float v0 = xr4.z + xl2.x; v0 = (v0 >= 0.0f) ? v0 : 0.2f * v0;
      float v1 = xr4.z + xl2.y; v1 = (v1 >= 0.0f) ? v1 : 0.2f * v1;
      float v2 = xr4.z + xl2.z; v2 = (v2 >= 0.0f) ? v2 : 0.2f * v2;
      float v3 = xr4.z + xl2.w; v3 = (v3 >= 0.0f) ? v3 : 0.2f * v3;
      acc0 += v0 * aw4.z; acc1 += v1 * aw4.z; acc2 += v2 * aw4.z; acc3 += v3 * aw4.z;
    }
    // c = c4*4+3
    {
      float v0 = xr4.w + xl3.x; v0 = (v0 >= 0.0f) ? v0 : 0.2f * v0;
      float v1 = xr4.w + xl3.y; v1 = (v1 >= 0.0f) ? v1 : 0.2f * v1;
      float v2 = xr4.w + xl3.z; v2 = (v2 >= 0.0f) ? v2 : 0.2f * v2;
      float v3 = xr4.w + xl3.w; v3 = (v3 >= 0.0f) ? v3 : 0.2f * v3;
      acc0 += v0 * aw4.w; acc1 += v1 * aw4.w; acc2 += v2 * aw4.w; acc3 += v3 * aw4.w;
    }
  }
  const int i = it * 16 + i_l;
  float* dst = e_ws + i * 2048 + h * 512 + jt * 64 + jq * 4;
  dst[0] = acc0; dst[1] = acc1; dst[2] = acc2; dst[3] = acc3;
}

// ---------------- gatS: softmax over j per (i, h), in-place on e_ws ------------
__global__ __launch_bounds__(256) void gatS_kernel(float* __restrict__ e_ws) {
  const int i = blockIdx.x, tid = threadIdx.x;
  __shared__ float red[4];
  float* er = e_ws + i * 2048;
  for (int h = 0; h < 4; h++) {
    float v0 = er[h * 512 + tid], v1 = er[h * 512 + 256 + tid];
    float m = block_red256(fmaxf(v0, v1), red, true);
    float e0 = expf(v0 - m), e1 = expf(v1 - m);
    float s = block_red256(e0 + e1, red, false);
    float inv = 1.0f / s;
    er[h * 512 + tid] = e0 * inv;
    er[h * 512 + 256 + tid] = e1 * inv;
  }
}

// ---------------- gatX2: x_emb = alpha @ xl + gbias; grid 512 ------------------
// it covers 4 i (al 8KB) x h(4). thread: cq=tid&15, jp=(tid>>4)&3, ip=tid>>6.
__global__ __launch_bounds__(256) void gatX2_kernel(
    const float* __restrict__ e_ws, const float* __restrict__ xl,
    const float* __restrict__ gbias, float* __restrict__ xemb) {
  const int it = blockIdx.x >> 2, h = blockIdx.x & 3;
  const int tid = threadIdx.x;
  const int cq = tid & 15, jp = (tid >> 4) & 3, ip = tid >> 6;
  __shared__ float al[4][512];   // 8KB alpha rows for this head
  for (int i = tid; i < 4 * 512; i += 256)
    al[i >> 9][i & 511] = e_ws[(it * 4 + (i >> 9)) * 2048 + h * 512 + (i & 511)];
  __syncthreads();
  float acc0 = 0.0f, acc1 = 0.0f, acc2 = 0.0f, acc3 = 0.0f;
  #pragma unroll 4
  for (int js = 0; js < 128; js++) {
    const int j = js * 4 + jp;
    float4 x4 = *(const float4*)&xl[j * 256 + h * 64 + cq * 4];
    float a = al[ip][j];
    acc0 += a * x4.x; acc1 += a * x4.y; acc2 += a * x4.z; acc3 += a * x4.w;
  }
  acc0 += __shfl_xor(acc0, 16, 64); acc0 += __shfl_xor(acc0, 32, 64);
  acc1 += __shfl_xor(acc1, 16, 64); acc1 += __shfl_xor(acc1, 32, 64);
  acc2 += __shfl_xor(acc2, 16, 64); acc2 += __shfl_xor(acc2, 32, 64);
  acc3 += __shfl_xor(acc3, 16, 64); acc3 += __shfl_xor(acc3, 32, 64);
  if (jp == 0) {
    const int i = it * 4 + ip;
    const int o = h * 64 + cq * 4;
    float4 v = make_float4(acc0 + gbias[o],     acc1 + gbias[o + 1],
                           acc2 + gbias[o + 2], acc3 + gbias[o + 3]);
    *(float4*)&xemb[i * 256 + o] = v;
  }
}

// ---------------- fallback fused GAT (2 targets/block) if ws too small ---------
__global__ __launch_bounds__(256) void gat_fused_kernel(
    const float* __restrict__ xl, const float* __restrict__ xr,
    const float* __restrict__ attw, const float* __restrict__ gbias,
    float* __restrict__ xemb) {
  const int i0 = blockIdx.x * 2, tid = threadIdx.x;
  __shared__ float xri[2][256];
  __shared__ float aw[256];
  __shared__ float e[2][4][NN];
  __shared__ float part[4][2][256];
  __shared__ float red[4];
  xri[0][tid] = xr[i0 * 256 + tid];
  xri[1][tid] = xr[(i0 + 1) * 256 + tid];
  aw[tid] = attw[tid];
  __syncthreads();
  #pragma unroll
  for (int jj = 0; jj < 2; jj++) {
    const int j = tid + jj * 256;
    const float4* xl4 = (const float4*)(xl + j * 256);
    #pragma unroll
    for (int hh = 0; hh < 4; hh++) {
      float accA = 0.0f, accB = 0.0f;
      #pragma unroll 4
      for (int c4 = 0; c4 < 16; c4++) {
        float4 v = xl4[hh * 16 + c4];
        const int cb = hh * 64 + c4 * 4;
        float w0 = aw[cb + 0], w1 = aw[cb + 1], w2 = aw[cb + 2], w3 = aw[cb + 3];
        float a0 = xri[0][cb + 0] + v.x; a0 = (a0 >= 0.0f) ? a0 : 0.2f * a0;
        float a1 = xri[0][cb + 1] + v.y; a1 = (a1 >= 0.0f) ? a1 : 0.2f * a1;
        float a2 = xri[0][cb + 2] + v.z; a2 = (a2 >= 0.0f) ? a2 : 0.2f * a2;
        float a3 = xri[0][cb + 3] + v.w; a3 = (a3 >= 0.0f) ? a3 : 0.2f * a3;
        accA += a0 * w0; accA += a1 * w1; accA += a2 * w2; accA += a3 * w3;
        float b0 = xri[1][cb + 0] + v.x; b0 = (b0 >= 0.0f) ? b0 : 0.2f * b0;
        float b1 = xri[1][cb + 1] + v.y; b1 = (b1 >= 0.0f) ? b1 : 0.2f * b1;
        float b2 = xri[1][cb + 2] + v.z; b2 = (b2 >= 0.0f) ? b2 : 0.2f * b2;
        float b3 = xri[1][cb + 3] + v.w; b3 = (b3 >= 0.0f) ? b3 : 0.2f * b3;
        accB += b0 * w0; accB += b1 * w1; accB += b2 * w2; accB += b3 * w3;
      }
      e[0][hh][j] = accA;
      e[1][hh][j] = accB;
    }
  }
  __syncthreads();
  for (int ii = 0; ii < 2; ii++) {
    for (int hh = 0; hh < 4; hh++) {
      float v0 = e[ii][hh][tid], v1 = e[ii][hh][tid + 256];
      float m = block_red256(fmaxf(v0, v1), red, true);
      float e0 = expf(v0 - m), e1 = expf(v1 - m);
      float ssum = block_red256(e0 + e1, red, false);
      float inv = 1.0f / ssum;
      e[ii][hh][tid] = e0 * inv;
      e[ii][hh][tid + 256] = e1 * inv;
    }
  }
  __syncthreads();
  {
    const int w = tid >> 6, lane = tid & 63;
    float a0 = 0.0f, a1 = 0.0f, a2 = 0.0f, a3 = 0.0f;
    float b0 = 0.0f, b1 = 0.0f, b2 = 0.0f, b3 = 0.0f;
    const int j0 = w * 128;
    for (int j = j0; j < j0 + 128; j++) {
      const float* xlr = xl + j * 256 + lane;
      float x0 = xlr[0], x1 = xlr[64], x2 = xlr[128], x3 = xlr[192];
      a0 += e[0][0][j] * x0; a1 += e[0][1][j] * x1;
      a2 += e[0][2][j] * x2; a3 += e[0][3][j] * x3;
      b0 += e[1][0][j] * x0; b1 += e[1][1][j] * x1;
      b2 += e[1][2][j] * x2; b3 += e[1][3][j] * x3;
    }
    part[w][0][lane]       = a0;
    part[w][0][64 + lane]  = a1;
    part[w][0][128 + lane] = a2;
    part[w][0][192 + lane] = a3;
    part[w][1][lane]       = b0;
    part[w][1][64 + lane]  = b1;
    part[w][1][128 + lane] = b2;
    part[w][1][192 + lane] = b3;
  }
  __syncthreads();
  {
    float accA = ((part[0][0][tid] + part[1][0][tid]) + part[2][0][tid]) + part[3][0][tid];
    float accB = ((part[0][1][tid] + part[1][1][tid]) + part[2][1][tid]) + part[3][1][tid];
    float gb = gbias[tid];
    xemb[i0 * 256 + tid] = accA + gb;
    xemb[(i0 + 1) * 256 + tid] = accB + gb;
  }
}

// ---------------- ml = x_emb @ gl_w + gl_b (tiled); mean/scale epilogue --------
__global__ __launch_bounds__(256) void glgemm_kernel(
    const float* __restrict__ xemb, const float* __restrict__ gl_w,
    const float* __restrict__ gl_b, float* __restrict__ out_mean,
    float* __restrict__ out_scale) {
  const int ct = blockIdx.x & 15, it = blockIdx.x >> 4;
  const int tid = threadIdx.x;
  const int i0 = it * 16, col = ct * 64 + (tid & 63), ti = tid >> 6;
  __shared__ float xe[16][LAT];   // 16KB
  for (int o = tid; o < 16 * LAT; o += 256) {
    xe[o >> 8][o & 255] = xemb[(i0 + (o >> 8)) * LAT + (o & 255)];
  }
  __syncthreads();
  const float bias = gl_b[col];
  float acc0 = bias, acc1 = bias, acc2 = bias, acc3 = bias;
  const int r0 = ti * 4;
  #pragma unroll 4
  for (int k = 0; k < LAT; k++) {
    float w = gl_w[k * 1024 + col];
    acc0 += xe[r0 + 0][k] * w;
    acc1 += xe[r0 + 1][k] * w;
    acc2 += xe[r0 + 2][k] * w;
    acc3 += xe[r0 + 3][k] * w;
  }
  float accs[4] = {acc0, acc1, acc2, acc3};
  if (col < 512) {
    #pragma unroll
    for (int q = 0; q < 4; q++) out_mean[(i0 + r0 + q) * NN + col] = accs[q];
  } else {
    #pragma unroll
    for (int q = 0; q < 4; q++) {
      float lv = fminf(fmaxf(accs[q], -5.0f), 2.0f);
      out_scale[(i0 + r0 + q) * NN + (col - 512)] = expf(0.5f * lv);
    }
  }
}

extern "C" void kernel_launch(void* const* d_in, const int* in_sizes, int n_in,
                              void* d_out, int out_size, void* d_ws, size_t ws_size,
                              hipStream_t stream) {
  (void)in_sizes; (void)n_in; (void)out_size;
  const float* X        = (const float*)d_in[0];
  const float* Z        = (const float*)d_in[1];
  const float* es_now   = (const float*)d_in[2];
  const float* es_lag   = (const float*)d_in[3];
  const float* prior    = (const float*)d_in[4];
  const float* wp1      = (const float*)d_in[5];
  const float* bp1      = (const float*)d_in[6];
  const float* enc_in_w = (const float*)d_in[7];
  const float* enc_in_b = (const float*)d_in[8];
  const float* enc_out_w= (const float*)d_in[9];
  const float* enc_out_b= (const float*)d_in[10];
  const float* enc_l1_w = (const float*)d_in[11];
  const float* enc_l1_b = (const float*)d_in[12];
  const float* enc_l2_w = (const float*)d_in[13];
  const float* enc_l2_b = (const float*)d_in[14];
  const float* enc_g1   = (const float*)d_in[15];
  const float* enc_b1   = (const float*)d_in[16];
  const float* enc_g2   = (const float*)d_in[17];
  const float* enc_b2   = (const float*)d_in[18];
  const float* wp2      = (const float*)d_in[19];
  const float* bp2      = (const float*)d_in[20];
  const float* fs_w     = (const float*)d_in[21];
  const float* fs_b     = (const float*)d_in[22];
  const float* ft_w     = (const float*)d_in[23];
  const float* ft_b     = (const float*)d_in[24];
  const float* gru_w_ih = (const float*)d_in[25];
  const float* gru_w_hh = (const float*)d_in[26];
  const float* gru_b_ih = (const float*)d_in[27];
  const float* gru_b_hh = (const float*)d_in[28];
  const float* tp_w     = (const float*)d_in[29];
  const float* tp_b     = (const float*)d_in[30];
  const float* ltn_w    = (const float*)d_in[31];
  const float* ltn_b    = (const float*)d_in[32];
  const float* gat_wl   = (const float*)d_in[33];
  const float* gat_bl   = (const float*)d_in[34];
  const float* gat_wr   = (const float*)d_in[35];
  const float* gat_br   = (const float*)d_in[36];
  const float* gat_att  = (const float*)d_in[37];
  const float* gat_bias = (const float*)d_in[38];
  const float* gl_w     = (const float*)d_in[39];
  const float* gl_b     = (const float*)d_in[40];
  const int*   tctx     = (const int*)d_in[41];

  float* out = (float*)d_out;
  float* ws  = (float*)d_ws;
  // ws layout (floats)
  float* x_inst   = ws;                // 64*512
  float* x_lag    = ws + 32768;        // 64*512
  float* z2p      = ws + 65536;        // 512*128
  float* z2f      = ws + 131072;       // 512*128
  float* xl       = ws + 196608;       // 512*256
  float* xr       = ws + 327680;       // 512*256
  float* gi_table = ws + 458752;       // 100*384
  float* xemb     = ws + 497152;       // 512*256
  float* x0       = ws + 628224;       // 640*64
  float* x_enc    = ws + 669184;       // 640*64
  float* zn_ws    = ws + 710144;       // 512*512
  float* e_ws     = ws + 972288;       // 512*2048 (4MB) — only if ws big enough
  float* w_hhT    = zn_ws;             // aliased; gru done before znA writes

  const bool big_ws = ws_size >= (size_t)(972288 + 512 * 2048) * 4;

  whht_kernel<<<dim3(192), dim3(256), 0, stream>>>(gru_w_hh, w_hhT);
  wp1_kernel<<<dim3(160), dim3(256), 0, stream>>>(X, wp1, bp1, x0);
  enc4_kernel<<<dim3(BAT), dim3(640), 0, stream>>>(
      x0, enc_in_w, enc_in_b, enc_out_w, enc_out_b,
      enc_l1_w, enc_l1_b, enc_l2_w, enc_l2_b,
      enc_g1, enc_b1, enc_g2, enc_b2, x_enc);
  wp2_kernel<<<dim3(128), dim3(256), 0, stream>>>(x_enc, wp2, bp2, x_inst, x_lag);
  adj_kernel<<<dim3(2 * NN), dim3(256), 0, stream>>>(
      x_inst, x_lag, es_now, es_lag, prior, out);
  gitab_kernel<<<dim3(100), dim3(384), 0, stream>>>(gru_w_ih, gru_b_ih, gi_table);
  flow_kernel<<<dim3(NN), dim3(128), 0, stream>>>(Z, fs_w, fs_b, ft_w, ft_b, z2p);
  gru_kernel6<<<dim3(NN), dim3(768), 0, stream>>>(
      tctx, w_hhT, gru_b_hh, gi_table, tp_w, tp_b, z2p, z2f);
  znA_kernel<<<dim3(512), dim3(256), 0, stream>>>(Z, z2f, ltn_w, ltn_b, zn_ws);
  znB_kernel<<<dim3(512), dim3(256), 0, stream>>>(
      zn_ws, gat_wl, gat_bl, gat_wr, gat_br, xl, xr);
  if (big_ws) {
    gatE4_kernel<<<dim3(1024), dim3(256), 0, stream>>>(xl, xr, gat_att, e_ws);
    gatS_kernel<<<dim3(NN), dim3(256), 0, stream>>>(e_ws);
    gatX2_kernel<<<dim3(512), dim3(256), 0, stream>>>(e_ws, xl, gat_bias, xemb);
  } else {
    gat_fused_kernel<<<dim3(NN / 2), dim3(256), 0, stream>>>(
        xl, xr, gat_att, gat_bias, xemb);
  }
  glgemm_kernel<<<dim3(512), dim3(256), 0, stream>>>(
      xemb, gl_w, gl_b, out + 2 * NN * NN, out + 3 * NN * NN);
}